// Round 18
// baseline (188.520 us; speedup 1.0000x reference)
//
#include <hip/hip_runtime.h>
#include <hip/hip_fp16.h>
#include <math.h>

#define NT 256
#define NT0 512
#define T_SIZE 524288u
#define T_MASK 524287u
#define PR1 2654435761u
#define PR2 805459861u

// wbuf (pre-staged bf16 weight planes) layout, in ushort units
#define OFF_WD1 0
#define OFF_WD2 4096
#define OFF_WS1 6144
#define OFF_WS2 18432
#define OFF_WT1 26624
#define OFF_WT2 30720
#define OFF_WT3 38912
#define WBUF_USH 47104
#define WBUF_BYTES 98304

// act stride: 104 ushorts (208B = 52 dwords; 52%32=20 -> 8 consecutive rows
// land on 8 disjoint 4-bank spans = all 32 banks -> conflict-free b128 reads)
#define AS 104

typedef float f32x4 __attribute__((ext_vector_type(4)));
typedef short s16x8 __attribute__((ext_vector_type(8)));
typedef unsigned u32x4 __attribute__((ext_vector_type(4)));

__device__ __forceinline__ float sigmoidf_(float x) { return 1.0f / (1.0f + __expf(-x)); }
__device__ __forceinline__ float softplusf_(float x) { return fmaxf(x, 0.0f) + log1pf(__expf(-fabsf(x))); }

__device__ __forceinline__ unsigned short f2bf(float f) {
  union { float f; unsigned u; } v; v.f = f;
  unsigned r = v.u + 0x7fffu + ((v.u >> 16) & 1u);
  return (unsigned short)(r >> 16);
}
__device__ __forceinline__ float bf2f(unsigned short h) {
  union { unsigned u; float f; } v; v.u = ((unsigned)h) << 16; return v.f;
}
__device__ __forceinline__ f32x4 splat4(float t) { f32x4 v; v[0]=t; v[1]=t; v[2]=t; v[3]=t; return v; }

__device__ __forceinline__ unsigned char f2e5(float f) {
  unsigned short u = __half_as_ushort(__float2half(f));
  return (unsigned char)(((unsigned)u + 0x7Fu + ((u >> 8) & 1u)) >> 8);
}
__device__ __forceinline__ float e52f(unsigned v) {
  return __half2float(__ushort_as_half((unsigned short)((v & 0xFFu) << 8)));
}

template <int ASTR, int SWM>
__device__ __forceinline__ s16x8 lda(const unsigned short* act, int lane, int m, int kh) {
  int p = m * 16 + (lane & 15);
  int c = (kh * 32 + ((lane >> 4) << 3)) ^ ((p & SWM) << 3);
  return *reinterpret_cast<const s16x8*>(act + p * ASTR + c);
}
__device__ __forceinline__ s16x8 ldb(const unsigned short* wb, int lane, int fidx) {
  return *reinterpret_cast<const s16x8*>(wb + (fidx * 64 + lane) * 8);
}
template <int ASTR, int SWM>
__device__ __forceinline__ void stp(unsigned short* act, int p, int col, float v0, float v1) {
  unsigned pk = (unsigned)f2bf(v0) | (((unsigned)f2bf(v1)) << 16);
  *reinterpret_cast<unsigned*>(act + p * ASTR + (col ^ ((p & SWM) << 3))) = pk;
}

template <int BT, int KH, int NTI, int NCOLS, class F>
__device__ void stage_plane(unsigned short* dst, const float* __restrict__ W, int plane, int tid, F rowmap) {
  for (int i = tid; i < NTI * KH * 64; i += BT) {
    int f = i >> 6, lane = i & 63;
    int n = f / KH, kh = f - n * KH;
    int o = n * 16 + (lane & 15);
    int kb = kh * 32 + ((lane >> 4) << 3);
    unsigned us0, us1, us2, us3;
#define MKPAIR(dstu, j0) { \
      unsigned short e0, e1; \
      { int sr = rowmap(kb + (j0)); float w = (sr >= 0) ? W[sr * NCOLS + o] : 0.f; \
        unsigned short hi = f2bf(w); e0 = plane ? f2bf(w - bf2f(hi)) : hi; } \
      { int sr = rowmap(kb + (j0) + 1); float w = (sr >= 0) ? W[sr * NCOLS + o] : 0.f; \
        unsigned short hi = f2bf(w); e1 = plane ? f2bf(w - bf2f(hi)) : hi; } \
      dstu = (unsigned)e0 | (((unsigned)e1) << 16); }
    MKPAIR(us0, 0) MKPAIR(us1, 2) MKPAIR(us2, 4) MKPAIR(us3, 6)
#undef MKPAIR
    *reinterpret_cast<uint4*>(dst + (size_t)i * 8) = make_uint4(us0, us1, us2, us3);
  }
}

template <int BT>
__device__ __forceinline__ void stage(float* dst, const float* __restrict__ src, int cnt, int tid) {
  for (int i = tid; i < cnt; i += BT) dst[i] = src[i];
}

template <int BT>
__device__ __forceinline__ void stagecpy(unsigned short* dst, const unsigned short* __restrict__ src,
                                         int cnt_ush, int tid) {
  const uint4* s = reinterpret_cast<const uint4*>(src);
  uint4* d = reinterpret_cast<uint4*>(dst);
  for (int i = tid; i < (cnt_ush >> 3); i += BT) d[i] = s[i];
}

#define MFMA_(a, b, c) __builtin_amdgcn_mfma_f32_16x16x32_bf16(a, b, c, 0, 0, 0)

#define DECL_ACC f32x4 acc00, acc01, acc02, acc03, acc10, acc11, acc12, acc13, \
                       acc20, acc21, acc22, acc23, acc30, acc31, acc32, acc33;

#define ACC_INIT(B) { \
  float t0 = (B)[(lane & 15)], t1 = (B)[16 + (lane & 15)], t2 = (B)[32 + (lane & 15)], t3 = (B)[48 + (lane & 15)]; \
  acc00 = splat4(t0); acc10 = acc00; acc20 = acc00; acc30 = acc00; \
  acc01 = splat4(t1); acc11 = acc01; acc21 = acc01; acc31 = acc01; \
  acc02 = splat4(t2); acc12 = acc02; acc22 = acc02; acc32 = acc02; \
  acc03 = splat4(t3); acc13 = acc03; acc23 = acc03; acc33 = acc03; }

#define GEMM_NBLK(WPTR, kh, KH, n) { s16x8 b = ldb(WPTR, lane, (n) * (KH) + (kh)); \
  acc0##n = MFMA_(a0, b, acc0##n); acc1##n = MFMA_(a1, b, acc1##n); \
  acc2##n = MFMA_(a2, b, acc2##n); acc3##n = MFMA_(a3, b, acc3##n); }

#define GEMM64(ACTP, ASTR, SWM, WB, KH, PLN) { \
  _Pragma("unroll") for (int kh = 0; kh < (KH); ++kh) { \
    s16x8 a0 = lda<ASTR, SWM>(ACTP, lane, 0, kh), a1 = lda<ASTR, SWM>(ACTP, lane, 1, kh), \
          a2 = lda<ASTR, SWM>(ACTP, lane, 2, kh), a3 = lda<ASTR, SWM>(ACTP, lane, 3, kh); \
    _Pragma("unroll") for (int pl = 0; pl < (PLN); ++pl) { \
      const unsigned short* wp = (WB) + pl * (KH) * 2048; \
      GEMM_NBLK(wp, kh, KH, 0) GEMM_NBLK(wp, kh, KH, 1) GEMM_NBLK(wp, kh, KH, 2) GEMM_NBLK(wp, kh, KH, 3) } } }

#define ST_ACT1(ACTP, ASTR, SWM, m, n, A) { \
  _Pragma("unroll") for (int r = 0; r < 4; ++r) { \
    int p = (m) * 16 + ((lane >> 4) << 2) + r; int col = (n) * 16 + (lane & 15); \
    (ACTP)[p * (ASTR) + (col ^ ((p & (SWM)) << 3))] = f2bf(fmaxf((A)[r], 0.f)); } }

#define ST_ACT_ALL(ACTP, ASTR, SWM) \
  ST_ACT1(ACTP, ASTR, SWM, 0, 0, acc00) ST_ACT1(ACTP, ASTR, SWM, 0, 1, acc01) \
  ST_ACT1(ACTP, ASTR, SWM, 0, 2, acc02) ST_ACT1(ACTP, ASTR, SWM, 0, 3, acc03) \
  ST_ACT1(ACTP, ASTR, SWM, 1, 0, acc10) ST_ACT1(ACTP, ASTR, SWM, 1, 1, acc11) \
  ST_ACT1(ACTP, ASTR, SWM, 1, 2, acc12) ST_ACT1(ACTP, ASTR, SWM, 1, 3, acc13) \
  ST_ACT1(ACTP, ASTR, SWM, 2, 0, acc20) ST_ACT1(ACTP, ASTR, SWM, 2, 1, acc21) \
  ST_ACT1(ACTP, ASTR, SWM, 2, 2, acc22) ST_ACT1(ACTP, ASTR, SWM, 2, 3, acc23) \
  ST_ACT1(ACTP, ASTR, SWM, 3, 0, acc30) ST_ACT1(ACTP, ASTR, SWM, 3, 1, acc31) \
  ST_ACT1(ACTP, ASTR, SWM, 3, 2, acc32) ST_ACT1(ACTP, ASTR, SWM, 3, 3, acc33)

#define ST_HV(ACTP, ASTR, SWM, m, H) { \
  _Pragma("unroll") for (int r = 0; r < 4; ++r) { \
    int pp = (m) * 16 + ((lane >> 4) << 2) + r; \
    (ACTP)[pp * (ASTR) + ((lane & 15) ^ ((pp & (SWM)) << 3))] = f2bf((H)[r]); } }

// ============ wprep body (shared by kprep and legacy kwprep) ============
__device__ void wprep_block(int pid, int tid,
                            const float* Wd1, const float* Wd2, const float* Ws1,
                            const float* Ws2, const float* Wt1, const float* Wt2,
                            const float* Wt3, unsigned short* wbuf) {
  const float* W;
  int KH, NTI, NCOLS, mapt, dst;
  switch (pid >> 1) {
    case 0: W = Wd1; KH = 1; NTI = 4; NCOLS = 64; mapt = 0; dst = OFF_WD1 + (pid & 1) * 2048; break;
    case 1: W = Wd2; KH = 2; NTI = 1; NCOLS = 16; mapt = 0; dst = OFF_WD2 + (pid & 1) * 1024; break;
    case 2: W = Ws1; KH = 3; NTI = 4; NCOLS = 64; mapt = 1; dst = OFF_WS1 + (pid & 1) * 6144; break;
    case 3: W = Ws2; KH = 2; NTI = 4; NCOLS = 64; mapt = 0; dst = OFF_WS2 + (pid & 1) * 4096; break;
    case 4: W = Wt1; KH = 1; NTI = 4; NCOLS = 64; mapt = 0; dst = OFF_WT1 + (pid & 1) * 2048; break;
    case 5: W = Wt2; KH = 2; NTI = 4; NCOLS = 64; mapt = 0; dst = OFF_WT2 + (pid & 1) * 4096; break;
    default: W = Wt3; KH = 2; NTI = 4; NCOLS = 64; mapt = 0; dst = OFF_WT3 + (pid & 1) * 4096; break;
  }
  const int plane = pid & 1;
  const int total = NTI * KH * 64;
  for (int i = tid; i < total; i += 256) {
    int f = i >> 6, lane = i & 63;
    int n = f / KH, kh = f - n * KH;
    int o = n * 16 + (lane & 15);
    int kb = kh * 32 + ((lane >> 4) << 3);
    unsigned short e[8];
#pragma unroll
    for (int j = 0; j < 8; ++j) {
      int k = kb + j;
      int sr = mapt ? (k < 16 ? k : (k < 64 ? 27 + k : (k < 91 ? k - 48 : -1))) : k;
      float w = (sr >= 0) ? W[sr * NCOLS + o] : 0.f;
      unsigned short hi = f2bf(w);
      e[j] = plane ? f2bf(w - bf2f(hi)) : hi;
    }
    uint4 v;
    v.x = (unsigned)e[0] | ((unsigned)e[1] << 16);
    v.y = (unsigned)e[2] | ((unsigned)e[3] << 16);
    v.z = (unsigned)e[4] | ((unsigned)e[5] << 16);
    v.w = (unsigned)e[6] | ((unsigned)e[7] << 16);
    *reinterpret_cast<uint4*>(wbuf + dst + (size_t)i * 8) = v;
  }
}

// ============ Kprep: fused weight prep (blocks 0..13) + fp8 table conv ============
__global__ void __launch_bounds__(256) kprep(
    const float* __restrict__ tables, unsigned* __restrict__ t8, int nq,
    const float* __restrict__ Wd1, const float* __restrict__ Wd2,
    const float* __restrict__ Ws1, const float* __restrict__ Ws2,
    const float* __restrict__ Wt1, const float* __restrict__ Wt2,
    const float* __restrict__ Wt3, unsigned short* __restrict__ wbuf) {
  if (blockIdx.x < 14) {
    wprep_block(blockIdx.x, threadIdx.x, Wd1, Wd2, Ws1, Ws2, Wt1, Wt2, Wt3, wbuf);
    return;
  }
  int i = (blockIdx.x - 14) * 256 + threadIdx.x;
  if (i >= nq) return;
  f32x4 v = __builtin_nontemporal_load(reinterpret_cast<const f32x4*>(tables) + i);
  unsigned r = (unsigned)f2e5(v[0]) | ((unsigned)f2e5(v[1]) << 8) |
               ((unsigned)f2e5(v[2]) << 16) | ((unsigned)f2e5(v[3]) << 24);
  __builtin_nontemporal_store(r, t8 + i);
}

// ============ legacy kwprep / kconv (fallback path) ============
__global__ void __launch_bounds__(256) kwprep(
    const float* __restrict__ Wd1, const float* __restrict__ Wd2,
    const float* __restrict__ Ws1, const float* __restrict__ Ws2,
    const float* __restrict__ Wt1, const float* __restrict__ Wt2,
    const float* __restrict__ Wt3, unsigned short* __restrict__ wbuf) {
  wprep_block(blockIdx.x, threadIdx.x, Wd1, Wd2, Ws1, Ws2, Wt1, Wt2, Wt3, wbuf);
}
__global__ void __launch_bounds__(256) kconv(const float* __restrict__ tables,
                                             unsigned* __restrict__ t8, int nq) {
  int i = blockIdx.x * 256 + threadIdx.x;
  if (i >= nq) return;
  f32x4 v = __builtin_nontemporal_load(reinterpret_cast<const f32x4*>(tables) + i);
  unsigned r = (unsigned)f2e5(v[0]) | ((unsigned)f2e5(v[1]) << 8) |
               ((unsigned)f2e5(v[2]) << 16) | ((unsigned)f2e5(v[3]) << 24);
  __builtin_nontemporal_store(r, t8 + i);
}

// ============ K0a: hash gather, asm pipeline + x-pair dword loads ============
// Request-rate-bound regime (r14-r17: two concurrency levers both saturated at
// 0.71 lane-req/cyc/CU). PRIMES[0]==1 => x-corner pair (i0,i0+1) shares one
// aligned dword when i0 even. 16 unconditional dword loads + 4 exec-masked
// blocks of 4 ushort loads (odd-i0 lanes only): avg 24 lane-requests vs 32.
// Single vmcnt(0) fence (conditional blocks make counted waits unsafe).
__global__ void __launch_bounds__(256, 4) k0a_gather(
    const float* __restrict__ x, const unsigned short* __restrict__ t8,
    unsigned* __restrict__ featws, int Npts) {
  const int lane = threadIdx.x & 63, wv = threadIdx.x >> 6;
  const int g = blockIdx.x & 3;
  const int n = (blockIdx.x >> 2) * 256 + wv * 64 + lane;
  if (n >= Npts) return;
  float xn0 = x[3 * n + 0] * 0.25f + 0.5f;
  float xn1 = x[3 * n + 1] * 0.25f + 0.5f;
  float xn2 = x[3 * n + 2] * 0.25f + 0.5f;

  float scA, scB, scC, scD;
  switch (g) {
    case 0:  scA = 16.f; scB = 58.f;  scC = 213.f; scD = 777.f;  break;
    case 1:  scA = 22.f; scB = 80.f;  scC = 295.f; scD = 1074.f; break;
    case 2:  scA = 30.f; scB = 111.f; scC = 407.f; scD = 1483.f; break;
    default: scA = 42.f; scB = 154.f; scC = 563.f; scD = 2048.f; break;
  }

  unsigned parmask = 0, oddmask = 0;

  // phase A: dword-pair addrs (da), odd-corner ushort addrs (ua), parity bits
#define ALVL(J, SC) \
  unsigned da##J##0, da##J##1, da##J##2, da##J##3; \
  unsigned ua##J##0, ua##J##1, ua##J##2, ua##J##3; \
  float lf##J##0, lf##J##1, lf##J##2; \
  { \
    float xs0 = xn0 * (SC), xs1 = xn1 * (SC), xs2 = xn2 * (SC); \
    float f0 = floorf(xs0), f1 = floorf(xs1), f2 = floorf(xs2); \
    lf##J##0 = xs0 - f0; lf##J##1 = xs1 - f1; lf##J##2 = xs2 - f2; \
    unsigned i0 = (unsigned)(int)f0, i1 = (unsigned)(int)f1, i2 = (unsigned)(int)f2; \
    unsigned i0p = i0 + 1u; \
    unsigned b0v = i1 * PR1, b1v = (i1 + 1u) * PR1; \
    unsigned c0v = i2 * PR2, c1v = (i2 + 1u) * PR2; \
    unsigned base = (unsigned)(g + 4 * (J)) * T_SIZE; \
    unsigned idx; \
    idx = base + ((i0 ^ b0v ^ c0v) & T_MASK); da##J##0 = (idx & ~1u) * 2u; parmask |= (idx & 1u) << ((J) * 4 + 0); \
    ua##J##0 = (base + ((i0p ^ b0v ^ c0v) & T_MASK)) * 2u; \
    idx = base + ((i0 ^ b1v ^ c0v) & T_MASK); da##J##1 = (idx & ~1u) * 2u; parmask |= (idx & 1u) << ((J) * 4 + 1); \
    ua##J##1 = (base + ((i0p ^ b1v ^ c0v) & T_MASK)) * 2u; \
    idx = base + ((i0 ^ b0v ^ c1v) & T_MASK); da##J##2 = (idx & ~1u) * 2u; parmask |= (idx & 1u) << ((J) * 4 + 2); \
    ua##J##2 = (base + ((i0p ^ b0v ^ c1v) & T_MASK)) * 2u; \
    idx = base + ((i0 ^ b1v ^ c1v) & T_MASK); da##J##3 = (idx & ~1u) * 2u; parmask |= (idx & 1u) << ((J) * 4 + 3); \
    ua##J##3 = (base + ((i0p ^ b1v ^ c1v) & T_MASK)) * 2u; \
    oddmask |= (i0 & 1u) << (J); \
  }
  ALVL(0, scA) ALVL(1, scB) ALVL(2, scC) ALVL(3, scD)
#undef ALVL

  // phase B1: 16 unconditional dword loads (asm volatile: order + liveness pinned)
#define GLDD(Q, AD) asm volatile("global_load_dword %0, %1, %2" : "=v"(Q) : "v"(AD), "s"(t8));
#define GLDU(Q, AD) asm volatile("global_load_ushort %0, %1, %2" : "=v"(Q) : "v"(AD), "s"(t8));
  unsigned D00, D01, D02, D03, D10, D11, D12, D13,
           D20, D21, D22, D23, D30, D31, D32, D33;
  GLDD(D00, da00) GLDD(D01, da01) GLDD(D02, da02) GLDD(D03, da03)
  GLDD(D10, da10) GLDD(D11, da11) GLDD(D12, da12) GLDD(D13, da13)
  GLDD(D20, da20) GLDD(D21, da21) GLDD(D22, da22) GLDD(D23, da23)
  GLDD(D30, da30) GLDD(D31, da31) GLDD(D32, da32) GLDD(D33, da33)

  // phase B2: odd-i0 corner-1 loads, exec-masked per level (~50% lanes active)
  unsigned U00 = 0, U01 = 0, U02 = 0, U03 = 0, U10 = 0, U11 = 0, U12 = 0, U13 = 0,
           U20 = 0, U21 = 0, U22 = 0, U23 = 0, U30 = 0, U31 = 0, U32 = 0, U33 = 0;
  if (oddmask & 1u) { GLDU(U00, ua00) GLDU(U01, ua01) GLDU(U02, ua02) GLDU(U03, ua03) }
  if (oddmask & 2u) { GLDU(U10, ua10) GLDU(U11, ua11) GLDU(U12, ua12) GLDU(U13, ua13) }
  if (oddmask & 4u) { GLDU(U20, ua20) GLDU(U21, ua21) GLDU(U22, ua22) GLDU(U23, ua23) }
  if (oddmask & 8u) { GLDU(U30, ua30) GLDU(U31, ua31) GLDU(U32, ua32) GLDU(U33, ua33) }
#undef GLDU
#undef GLDD
  asm volatile("s_waitcnt vmcnt(0)" ::: "memory");
  __builtin_amdgcn_sched_barrier(0);

  // phase C: merge + blend (values bit-identical to the 8-ushort path)
#define MERGE(J, K, D, U, Q0, Q1) \
  unsigned Q0, Q1; \
  { \
    unsigned hi = (parmask >> ((J) * 4 + (K))) & 1u; \
    unsigned lo16 = (D) & 0xffffu, hi16 = (D) >> 16; \
    Q0 = hi ? hi16 : lo16; \
    unsigned other = hi ? lo16 : hi16; \
    Q1 = ((oddmask >> (J)) & 1u) ? (U) : other; \
  }
#define BLVL(J, FP) { \
    MERGE(J, 0, D##J##0, U##J##0, q##J##0, q##J##1) \
    MERGE(J, 1, D##J##1, U##J##1, q##J##2, q##J##3) \
    MERGE(J, 2, D##J##2, U##J##2, q##J##4, q##J##5) \
    MERGE(J, 3, D##J##3, U##J##3, q##J##6, q##J##7) \
    float w1x = lf##J##0, w0x = 1.f - w1x; \
    float w1y = lf##J##1, w0y = 1.f - w1y; \
    float w1z = lf##J##2, w0z = 1.f - w1z; \
    float w000 = w0x * w0y * w0z, w100 = w1x * w0y * w0z; \
    float w010 = w0x * w1y * w0z, w110 = w1x * w1y * w0z; \
    float w001 = w0x * w0y * w1z, w101 = w1x * w0y * w1z; \
    float w011 = w0x * w1y * w1z, w111 = w1x * w1y * w1z; \
    float fa = w000 * e52f(q##J##0) + w100 * e52f(q##J##1) + w010 * e52f(q##J##2) + \
               w110 * e52f(q##J##3) + w001 * e52f(q##J##4) + w101 * e52f(q##J##5) + \
               w011 * e52f(q##J##6) + w111 * e52f(q##J##7); \
    float fb = w000 * e52f(q##J##0 >> 8) + w100 * e52f(q##J##1 >> 8) + w010 * e52f(q##J##2 >> 8) + \
               w110 * e52f(q##J##3 >> 8) + w001 * e52f(q##J##4 >> 8) + w101 * e52f(q##J##5 >> 8) + \
               w011 * e52f(q##J##6 >> 8) + w111 * e52f(q##J##7 >> 8); \
    FP = (unsigned)f2bf(fa) | (((unsigned)f2bf(fb)) << 16); }
  unsigned fp0, fp1, fp2, fp3;
  BLVL(0, fp0) BLVL(1, fp1) BLVL(2, fp2) BLVL(3, fp3)
#undef BLVL
#undef MERGE
  u32x4 o; o[0] = fp0; o[1] = fp1; o[2] = fp2; o[3] = fp3;
  __builtin_nontemporal_store(
      o, reinterpret_cast<u32x4*>(featws + ((size_t)g * Npts + n) * 4));
}

// ============ K12b: fused density + static + transient (stride-104 acts) ============
__global__ void __launch_bounds__(NT, 2) k12b_all(
    const float* __restrict__ x, const float* __restrict__ d,
    const int* __restrict__ aidx, const int* __restrict__ tridx,
    const float* __restrict__ emb_a, const float* __restrict__ emb_t,
    const unsigned* __restrict__ featws, const unsigned short* __restrict__ wbuf,
    const float* __restrict__ bd1, const float* __restrict__ bd2,
    const float* __restrict__ bs1, const float* __restrict__ bs2,
    const float* __restrict__ Ws3, const float* __restrict__ bs3,
    const float* __restrict__ bt1, const float* __restrict__ bt2,
    const float* __restrict__ bt3,
    const float* __restrict__ Wtd, const float* __restrict__ btd,
    const float* __restrict__ Wtr, const float* __restrict__ btr,
    const float* __restrict__ Wtb, const float* __restrict__ btb,
    float* __restrict__ out, int Npts) {
  __shared__ __align__(16) unsigned short sh[38912];  // acts 4x64x104=26624 | wreg 12288
  __shared__ __align__(16) float fl[984];
  const int tid = threadIdx.x, lane = tid & 63, wv = tid >> 6;
  const int n = blockIdx.x * NT + tid;
  const bool live = (n < Npts);
  const int nn = live ? n : Npts - 1;
  unsigned short* actw = sh + wv * (64 * AS);
  unsigned short* wreg = sh + 26624;
  float* exch = reinterpret_cast<float*>(wreg + 6144);
  const int p = lane;

  float xn0 = x[3 * nn + 0] * 0.25f, xn1 = x[3 * nn + 1] * 0.25f, xn2 = x[3 * nn + 2] * 0.25f;
  const bool mask = (fabsf(xn0) < 0.5f) && (fabsf(xn1) < 0.5f) && (fabsf(xn2) < 0.5f);

  u32x4 q0 = __builtin_nontemporal_load(
      reinterpret_cast<const u32x4*>(featws + ((size_t)0 * Npts + nn) * 4));
  u32x4 q1 = __builtin_nontemporal_load(
      reinterpret_cast<const u32x4*>(featws + ((size_t)1 * Npts + nn) * 4));
  u32x4 q2 = __builtin_nontemporal_load(
      reinterpret_cast<const u32x4*>(featws + ((size_t)2 * Npts + nn) * 4));
  u32x4 q3 = __builtin_nontemporal_load(
      reinterpret_cast<const u32x4*>(featws + ((size_t)3 * Npts + nn) * 4));
  const float4* tp = reinterpret_cast<const float4*>(emb_t + (size_t)tridx[nn] * 16);
  float4 et0 = tp[0], et1 = tp[1], et2 = tp[2], et3 = tp[3];

  {
    float d0 = d[3 * nn + 0], d1 = d[3 * nn + 1], d2 = d[3 * nn + 2];
    float s10 = __sinf(d0), s11 = __sinf(d1), s12 = __sinf(d2);
    float c10 = __cosf(d0), c11 = __cosf(d1), c12 = __cosf(d2);
    float s20 = __sinf(2.f * d0), s21 = __sinf(2.f * d1), s22 = __sinf(2.f * d2);
    float c20 = __cosf(2.f * d0), c21 = __cosf(2.f * d1), c22 = __cosf(2.f * d2);
    float s40 = __sinf(4.f * d0), s41 = __sinf(4.f * d1), s42 = __sinf(4.f * d2);
    float c40 = __cosf(4.f * d0), c41 = __cosf(4.f * d1), c42 = __cosf(4.f * d2);
    float s80 = __sinf(8.f * d0), s81 = __sinf(8.f * d1), s82 = __sinf(8.f * d2);
    float c80 = __cosf(8.f * d0), c81 = __cosf(8.f * d1), c82 = __cosf(8.f * d2);
    stp<AS, 0>(actw, p, 64, d0, d1);   stp<AS, 0>(actw, p, 66, d2, s10);
    stp<AS, 0>(actw, p, 68, s11, s12); stp<AS, 0>(actw, p, 70, c10, c11);
    stp<AS, 0>(actw, p, 72, c12, s20); stp<AS, 0>(actw, p, 74, s21, s22);
    stp<AS, 0>(actw, p, 76, c20, c21); stp<AS, 0>(actw, p, 78, c22, s40);
    stp<AS, 0>(actw, p, 80, s41, s42); stp<AS, 0>(actw, p, 82, c40, c41);
    stp<AS, 0>(actw, p, 84, c42, s80); stp<AS, 0>(actw, p, 86, s81, s82);
    stp<AS, 0>(actw, p, 88, c80, c81); stp<AS, 0>(actw, p, 90, c82, 0.f);
    stp<AS, 0>(actw, p, 92, 0.f, 0.f); stp<AS, 0>(actw, p, 94, 0.f, 0.f);
  }
#define PUTL(l, val) *reinterpret_cast<unsigned*>(actw + p * AS + 2 * (l)) = (val);
  PUTL(0, q0[0]) PUTL(4, q0[1]) PUTL(8, q0[2]) PUTL(12, q0[3])
  PUTL(1, q1[0]) PUTL(5, q1[1]) PUTL(9, q1[2]) PUTL(13, q1[3])
  PUTL(2, q2[0]) PUTL(6, q2[1]) PUTL(10, q2[2]) PUTL(14, q2[3])
  PUTL(3, q3[0]) PUTL(7, q3[1]) PUTL(11, q3[2]) PUTL(15, q3[3])
#undef PUTL

  stagecpy<NT>(wreg, wbuf + OFF_WD1, 4096, tid);
  stagecpy<NT>(wreg + 4096, wbuf + OFF_WD2, 2048, tid);
  stage<NT>(fl, bs1, 64, tid);
  stage<NT>(fl + 64, bs2, 64, tid);
  stage<NT>(fl + 128, Ws3, 192, tid);
  if (tid < 3) fl[320 + tid] = bs3[tid];
  stage<NT>(fl + 384, bt1, 64, tid);
  stage<NT>(fl + 448, bt2, 64, tid);
  stage<NT>(fl + 512, bt3, 64, tid);
  stage<NT>(fl + 576, Wtd, 64, tid);
  stage<NT>(fl + 640, Wtr, 192, tid);
  stage<NT>(fl + 832, Wtb, 64, tid);
  if (tid == 0) { fl[896] = btd[0]; fl[900] = btb[0]; }
  if (tid < 3) fl[897 + tid] = btr[tid];
  stage<NT>(fl + 904, bd1, 64, tid);
  stage<NT>(fl + 968, bd2, 16, tid);
  __syncthreads();

  // ---- density ----
  DECL_ACC;
  ACC_INIT(fl + 904);
  GEMM64(actw, AS, 0, wreg, 1, 2);
  ST_ACT_ALL(actw, AS, 0);

  f32x4 h0, h1, h2, h3;
  { float t = fl[968 + (lane & 15)]; h0 = splat4(t); h1 = h0; h2 = h0; h3 = h0; }
#pragma unroll
  for (int kh = 0; kh < 2; ++kh) {
    s16x8 a0 = lda<AS, 0>(actw, lane, 0, kh), a1 = lda<AS, 0>(actw, lane, 1, kh),
          a2 = lda<AS, 0>(actw, lane, 2, kh), a3 = lda<AS, 0>(actw, lane, 3, kh);
#pragma unroll
    for (int pl = 0; pl < 2; ++pl) {
      s16x8 b = ldb(wreg + 4096 + pl * 1024, lane, kh);
      h0 = MFMA_(a0, b, h0); h1 = MFMA_(a1, b, h1); h2 = MFMA_(a2, b, h2); h3 = MFMA_(a3, b, h3);
    }
  }
#define HV_X(m, H) { _Pragma("unroll") for (int r = 0; r < 4; ++r) { \
    int pr = (m) * 16 + ((lane >> 4) << 2) + r; \
    if ((lane & 15) == 0) exch[wv * 64 + pr] = (H)[r]; } }
  HV_X(0, h0) HV_X(1, h1) HV_X(2, h2) HV_X(3, h3)
#undef HV_X
  ST_HV(actw, AS, 0, 0, h0) ST_HV(actw, AS, 0, 1, h1)
  ST_HV(actw, AS, 0, 2, h2) ST_HV(actw, AS, 0, 3, h3)
  {
    float hv0v = exch[wv * 64 + lane];
    if (live) out[3 * (size_t)Npts + n] = mask ? __expf(hv0v) : 0.f;
  }
  {
    const float4* ap = reinterpret_cast<const float4*>(emb_a + (size_t)aidx[nn] * 48);
#pragma unroll
    for (int q = 0; q < 12; ++q) {
      float4 e = ap[q];
      stp<AS, 0>(actw, p, 16 + 4 * q, e.x, e.y);
      stp<AS, 0>(actw, p, 18 + 4 * q, e.z, e.w);
    }
  }
  __syncthreads();
  stagecpy<NT>(wreg, wbuf + OFF_WS1, 12288, tid);
  __syncthreads();

  // ---- static head ----
  ACC_INIT(fl);
  GEMM64(actw, AS, 0, wreg, 3, 2);
  ST_ACT_ALL(actw, AS, 0);
  __syncthreads();
  stagecpy<NT>(wreg, wbuf + OFF_WS2, 8192, tid);
  __syncthreads();
  ACC_INIT(fl + 64);
  GEMM64(actw, AS, 0, wreg, 2, 2);
  ST_ACT_ALL(actw, AS, 0);

  {
    float r0 = fl[320], r1 = fl[321], r2 = fl[322];
    for (int j = 0; j < 64; ++j) {
      int jj = (j + 2 * p) & 63;
      float a = bf2f(actw[p * AS + jj]);
      r0 = fmaf(a, fl[128 + 3 * jj + 0], r0);
      r1 = fmaf(a, fl[128 + 3 * jj + 1], r1);
      r2 = fmaf(a, fl[128 + 3 * jj + 2], r2);
    }
    if (live) {
      out[3 * (size_t)n + 0] = mask ? sigmoidf_(r0) : 0.f;
      out[3 * (size_t)n + 1] = mask ? sigmoidf_(r1) : 0.f;
      out[3 * (size_t)n + 2] = mask ? sigmoidf_(r2) : 0.f;
    }
  }

  // ---- transient ----
  ST_HV(actw, AS, 0, 0, h0) ST_HV(actw, AS, 0, 1, h1)
  ST_HV(actw, AS, 0, 2, h2) ST_HV(actw, AS, 0, 3, h3)
  stp<AS, 0>(actw, p, 16, et0.x, et0.y);  stp<AS, 0>(actw, p, 18, et0.z, et0.w);
  stp<AS, 0>(actw, p, 20, et1.x, et1.y);  stp<AS, 0>(actw, p, 22, et1.z, et1.w);
  stp<AS, 0>(actw, p, 24, et2.x, et2.y);  stp<AS, 0>(actw, p, 26, et2.z, et2.w);
  stp<AS, 0>(actw, p, 28, et3.x, et3.y);  stp<AS, 0>(actw, p, 30, et3.z, et3.w);
  __syncthreads();
  stagecpy<NT>(wreg, wbuf + OFF_WT1, 4096, tid);
  stagecpy<NT>(wreg + 4096, wbuf + OFF_WT2, 8192, tid);
  __syncthreads();
  ACC_INIT(fl + 384);
  GEMM64(actw, AS, 0, wreg, 1, 2);
  ST_ACT_ALL(actw, AS, 0);
  ACC_INIT(fl + 448);
  GEMM64(actw, AS, 0, (wreg + 4096), 2, 2);
  ST_ACT_ALL(actw, AS, 0);
  __syncthreads();
  stagecpy<NT>(wreg, wbuf + OFF_WT3, 8192, tid);
  __syncthreads();
  ACC_INIT(fl + 512);
  GEMM64(actw, AS, 0, wreg, 2, 2);
  ST_ACT_ALL(actw, AS, 0);

  float hd = fl[896], hr0 = fl[897], hr1 = fl[898], hr2 = fl[899], hb = fl[900];
  for (int j = 0; j < 64; ++j) {
    int jj = (j + 2 * p) & 63;
    float a = bf2f(actw[p * AS + jj]);
    hd = fmaf(a, fl[576 + jj], hd);
    hr0 = fmaf(a, fl[640 + 3 * jj + 0], hr0);
    hr1 = fmaf(a, fl[640 + 3 * jj + 1], hr1);
    hr2 = fmaf(a, fl[640 + 3 * jj + 2], hr2);
    hb = fmaf(a, fl[832 + jj], hb);
  }
  if (live) {
    size_t N4 = (size_t)Npts * 4;
    out[N4 + 3 * (size_t)n + 0] = mask ? sigmoidf_(hr0) : 0.f;
    out[N4 + 3 * (size_t)n + 1] = mask ? sigmoidf_(hr1) : 0.f;
    out[N4 + 3 * (size_t)n + 2] = mask ? sigmoidf_(hr2) : 0.f;
    out[(size_t)Npts * 7 + n] = mask ? __expf(softplusf_(hd)) : 0.f;
    out[(size_t)Npts * 8 + n] = mask ? (softplusf_(hb) + 0.1f) : 0.1f;
  }
}

// ============ K0f: fused fallback (self-staging, writes hvws) ============
template <int F8>
__global__ void __launch_bounds__(NT0, 4) k0f_density(
    const float* __restrict__ x, const float* __restrict__ tables,
    const unsigned short* __restrict__ t8,
    const float* __restrict__ Wd1, const float* __restrict__ bd1,
    const float* __restrict__ Wd2, const float* __restrict__ bd2,
    float* __restrict__ hvws, float* __restrict__ out, int Npts) {
  __shared__ __align__(16) unsigned short sh[38912];
  __shared__ __align__(16) float fl[592];
  const int tid = threadIdx.x, lane = tid & 63, wv = tid >> 6;
  const int n = blockIdx.x * NT0 + tid;
  const bool live = (n < Npts);
  const int nn = live ? n : Npts - 1;

  stage_plane<NT0, 1, 4, 64>(sh + 32768, Wd1, 0, tid, [](int k) { return k; });
  stage_plane<NT0, 1, 4, 64>(sh + 32768 + 2048, Wd1, 1, tid, [](int k) { return k; });
  stage_plane<NT0, 2, 1, 16>(sh + 36864, Wd2, 0, tid, [](int k) { return k; });
  stage_plane<NT0, 2, 1, 16>(sh + 36864 + 1024, Wd2, 1, tid, [](int k) { return k; });
  stage<NT0>(fl, bd1, 64, tid);
  stage<NT0>(fl + 64, bd2, 16, tid);
  __syncthreads();

  unsigned short* actw = sh + wv * 4096;
  const int p = lane;
  float xn0 = x[3 * nn + 0] * 0.25f + 0.5f, xn1 = x[3 * nn + 1] * 0.25f + 0.5f, xn2 = x[3 * nn + 2] * 0.25f + 0.5f;
  const bool mask = (fabsf(xn0 - 0.5f) < 0.5f) && (fabsf(xn1 - 0.5f) < 0.5f) && (fabsf(xn2 - 0.5f) < 0.5f);

  const float2* tab2 = reinterpret_cast<const float2*>(tables);
  constexpr float NLV[16] = {16.f, 22.f, 30.f, 42.f, 58.f, 80.f, 111.f, 154.f,
                             213.f, 295.f, 407.f, 563.f, 777.f, 1074.f, 1483.f, 2048.f};
#pragma unroll
  for (int l = 0; l < 16; ++l) {
    const float sc = NLV[l];
    float xs0 = xn0 * sc, xs1 = xn1 * sc, xs2 = xn2 * sc;
    float f0 = floorf(xs0), f1 = floorf(xs1), f2 = floorf(xs2);
    float l0 = xs0 - f0, l1 = xs1 - f1, l2 = xs2 - f2;
    unsigned i0 = (unsigned)(int)f0, i1 = (unsigned)(int)f1, i2 = (unsigned)(int)f2;
    unsigned a0 = i0, a1 = i0 + 1u;
    unsigned b0 = i1 * PR1, b1 = (i1 + 1u) * PR1;
    unsigned c0 = i2 * PR2, c1 = (i2 + 1u) * PR2;
    float w0x = 1.f - l0, w1x = l0, w0y = 1.f - l1, w1y = l1, w0z = 1.f - l2, w1z = l2;
    float2 t0, t1, t2, t3, t4, t5, t6, t7;
    if constexpr (F8) {
      const unsigned short* tl8 = t8 + (size_t)l * T_SIZE;
      unsigned short q0 = tl8[(a0 ^ b0 ^ c0) & T_MASK];
      unsigned short q1 = tl8[(a1 ^ b0 ^ c0) & T_MASK];
      unsigned short q2 = tl8[(a0 ^ b1 ^ c0) & T_MASK];
      unsigned short q3 = tl8[(a1 ^ b1 ^ c0) & T_MASK];
      unsigned short q4 = tl8[(a0 ^ b0 ^ c1) & T_MASK];
      unsigned short q5 = tl8[(a1 ^ b0 ^ c1) & T_MASK];
      unsigned short q6 = tl8[(a0 ^ b1 ^ c1) & T_MASK];
      unsigned short q7 = tl8[(a1 ^ b1 ^ c1) & T_MASK];
      t0 = make_float2(e52f(q0), e52f(q0 >> 8));
      t1 = make_float2(e52f(q1), e52f(q1 >> 8));
      t2 = make_float2(e52f(q2), e52f(q2 >> 8));
      t3 = make_float2(e52f(q3), e52f(q3 >> 8));
      t4 = make_float2(e52f(q4), e52f(q4 >> 8));
      t5 = make_float2(e52f(q5), e52f(q5 >> 8));
      t6 = make_float2(e52f(q6), e52f(q6 >> 8));
      t7 = make_float2(e52f(q7), e52f(q7 >> 8));
    } else {
      const float2* tl = tab2 + (size_t)l * T_SIZE;
      t0 = tl[(a0 ^ b0 ^ c0) & T_MASK];
      t1 = tl[(a1 ^ b0 ^ c0) & T_MASK];
      t2 = tl[(a0 ^ b1 ^ c0) & T_MASK];
      t3 = tl[(a1 ^ b1 ^ c0) & T_MASK];
      t4 = tl[(a0 ^ b0 ^ c1) & T_MASK];
      t5 = tl[(a1 ^ b0 ^ c1) & T_MASK];
      t6 = tl[(a0 ^ b1 ^ c1) & T_MASK];
      t7 = tl[(a1 ^ b1 ^ c1) & T_MASK];
    }
    float w000 = w0x * w0y * w0z, w100 = w1x * w0y * w0z;
    float w010 = w0x * w1y * w0z, w110 = w1x * w1y * w0z;
    float w001 = w0x * w0y * w1z, w101 = w1x * w0y * w1z;
    float w011 = w0x * w1y * w1z, w111 = w1x * w1y * w1z;
    float fa = w000 * t0.x + w100 * t1.x + w010 * t2.x + w110 * t3.x +
               w001 * t4.x + w101 * t5.x + w011 * t6.x + w111 * t7.x;
    float fb = w000 * t0.y + w100 * t1.y + w010 * t2.y + w110 * t3.y +
               w001 * t4.y + w101 * t5.y + w011 * t6.y + w111 * t7.y;
    unsigned pk = (unsigned)f2bf(fa) | (((unsigned)f2bf(fb)) << 16);
    *reinterpret_cast<unsigned*>(actw + p * 64 + ((2 * l) ^ ((p & 7) << 3))) = pk;
  }

  DECL_ACC;
  ACC_INIT(fl);
  GEMM64(actw, 64, 7, sh + 32768, 1, 2);
  ST_ACT_ALL(actw, 64, 7);

  f32x4 h0, h1, h2, h3;
  { float t = fl[64 + (lane & 15)]; h0 = splat4(t); h1 = h0; h2 = h0; h3 = h0; }
  {
#pragma unroll
    for (int kh = 0; kh < 2; ++kh) {
      s16x8 a0 = lda<64, 7>(actw, lane, 0, kh), a1 = lda<64, 7>(actw, lane, 1, kh),
            a2 = lda<64, 7>(actw, lane, 2, kh), a3 = lda<64, 7>(actw, lane, 3, kh);
#pragma unroll
      for (int pl = 0; pl < 2; ++pl) {
        s16x8 b = ldb(sh + 36864 + pl * 1024, lane, kh);
        h0 = MFMA_(a0, b, h0); h1 = MFMA_(a1, b, h1); h2 = MFMA_(a2, b, h2); h3 = MFMA_(a3, b, h3);
      }
    }
  }
  const int ptbase = blockIdx.x * NT0 + wv * 64;
#define HV_ST(m, H) { _Pragma("unroll") for (int r = 0; r < 4; ++r) { \
    int pr = (m) * 16 + ((lane >> 4) << 2) + r; \
    if (ptbase + pr < Npts) hvws[(size_t)(ptbase + pr) * 16 + (lane & 15)] = (H)[r]; \
    if ((lane & 15) == 0) fl[80 + wv * 64 + pr] = (H)[r]; } }
  HV_ST(0, h0) HV_ST(1, h1) HV_ST(2, h2) HV_ST(3, h3)
#undef HV_ST
  float hv0 = fl[80 + wv * 64 + lane];
  if (live) out[3 * (size_t)Npts + n] = mask ? __expf(hv0) : 0.f;
}

// ============ K12 legacy (fallback path, reads hvws) ============
__global__ void __launch_bounds__(NT, 2) k12_heads(
    const float* __restrict__ x, const float* __restrict__ d,
    const int* __restrict__ aidx, const int* __restrict__ tridx,
    const float* __restrict__ emb_a, const float* __restrict__ emb_t,
    const unsigned short* __restrict__ wbuf,
    const float* __restrict__ bs1, const float* __restrict__ bs2,
    const float* __restrict__ Ws3, const float* __restrict__ bs3,
    const float* __restrict__ bt1, const float* __restrict__ bt2,
    const float* __restrict__ bt3,
    const float* __restrict__ Wtd, const float* __restrict__ btd,
    const float* __restrict__ Wtr, const float* __restrict__ btr,
    const float* __restrict__ Wtb, const float* __restrict__ btb,
    const float* __restrict__ hvws, float* __restrict__ out, int Npts) {
  __shared__ __align__(16) unsigned short sh[36864];
  __shared__ __align__(16) float fl[904];
  const int tid = threadIdx.x, lane = tid & 63, wv = tid >> 6;
  const int n = blockIdx.x * NT + tid;
  const bool live = (n < Npts);
  const int nn = live ? n : Npts - 1;
  unsigned short* actw = sh + wv * 6144;
  const int p = lane;

  float xn0 = x[3 * nn + 0] * 0.25f, xn1 = x[3 * nn + 1] * 0.25f, xn2 = x[3 * nn + 2] * 0.25f;
  const bool mask = (fabsf(xn0) < 0.5f) && (fabsf(xn1) < 0.5f) && (fabsf(xn2) < 0.5f);

  const float4* hvp = reinterpret_cast<const float4*>(hvws + (size_t)nn * 16);
  float4 hv0_ = hvp[0], hv1_ = hvp[1], hv2_ = hvp[2], hv3_ = hvp[3];
  const float4* tp = reinterpret_cast<const float4*>(emb_t + (size_t)tridx[nn] * 16);
  float4 et0 = tp[0], et1 = tp[1], et2 = tp[2], et3 = tp[3];

  {
    stp<96, 3>(actw, p, 0, hv0_.x, hv0_.y);   stp<96, 3>(actw, p, 2, hv0_.z, hv0_.w);
    stp<96, 3>(actw, p, 4, hv1_.x, hv1_.y);   stp<96, 3>(actw, p, 6, hv1_.z, hv1_.w);
    stp<96, 3>(actw, p, 8, hv2_.x, hv2_.y);   stp<96, 3>(actw, p, 10, hv2_.z, hv2_.w);
    stp<96, 3>(actw, p, 12, hv3_.x, hv3_.y);  stp<96, 3>(actw, p, 14, hv3_.z, hv3_.w);
    const float4* ap = reinterpret_cast<const float4*>(emb_a + (size_t)aidx[nn] * 48);
#pragma unroll
    for (int q = 0; q < 12; ++q) {
      float4 e = ap[q];
      stp<96, 3>(actw, p, 16 + 4 * q, e.x, e.y);
      stp<96, 3>(actw, p, 18 + 4 * q, e.z, e.w);
    }
    float d0 = d[3 * nn + 0], d1 = d[3 * nn + 1], d2 = d[3 * nn + 2];
    float s10 = __sinf(d0), s11 = __sinf(d1), s12 = __sinf(d2);
    float c10 = __cosf(d0), c11 = __cosf(d1), c12 = __cosf(d2);
    float s20 = __sinf(2.f * d0), s21 = __sinf(2.f * d1), s22 = __sinf(2.f * d2);
    float c20 = __cosf(2.f * d0), c21 = __cosf(2.f * d1), c22 = __cosf(2.f * d2);
    float s40 = __sinf(4.f * d0), s41 = __sinf(4.f * d1), s42 = __sinf(4.f * d2);
    float c40 = __cosf(4.f * d0), c41 = __cosf(4.f * d1), c42 = __cosf(4.f * d2);
    float s80 = __sinf(8.f * d0), s81 = __sinf(8.f * d1), s82 = __sinf(8.f * d2);
    float c80 = __cosf(8.f * d0), c81 = __cosf(8.f * d1), c82 = __cosf(8.f * d2);
    stp<96, 3>(actw, p, 64, d0, d1);   stp<96, 3>(actw, p, 66, d2, s10);
    stp<96, 3>(actw, p, 68, s11, s12); stp<96, 3>(actw, p, 70, c10, c11);
    stp<96, 3>(actw, p, 72, c12, s20); stp<96, 3>(actw, p, 74, s21, s22);
    stp<96, 3>(actw, p, 76, c20, c21); stp<96, 3>(actw, p, 78, c22, s40);
    stp<96, 3>(actw, p, 80, s41, s42); stp<96, 3>(actw, p, 82, c40, c41);
    stp<96, 3>(actw, p, 84, c42, s80); stp<96, 3>(actw, p, 86, s81, s82);
    stp<96, 3>(actw, p, 88, c80, c81); stp<96, 3>(actw, p, 90, c82, 0.f);
    stp<96, 3>(actw, p, 92, 0.f, 0.f); stp<96, 3>(actw, p, 94, 0.f, 0.f);
  }
  stagecpy<NT>(sh + 24576, wbuf + OFF_WS1, 12288, tid);
  stage<NT>(fl, bs1, 64, tid);
  stage<NT>(fl + 64, bs2, 64, tid);
  stage<NT>(fl + 128, Ws3, 192, tid);
  if (tid < 3) fl[320 + tid] = bs3[tid];
  stage<NT>(fl + 384, bt1, 64, tid);
  stage<NT>(fl + 448, bt2, 64, tid);
  stage<NT>(fl + 512, bt3, 64, tid);
  stage<NT>(fl + 576, Wtd, 64, tid);
  stage<NT>(fl + 640, Wtr, 192, tid);
  stage<NT>(fl + 832, Wtb, 64, tid);
  if (tid == 0) { fl[896] = btd[0]; fl[900] = btb[0]; }
  if (tid < 3) fl[897 + tid] = btr[tid];
  __syncthreads();

  DECL_ACC;
  ACC_INIT(fl);
  GEMM64(actw, 96, 3, sh + 24576, 3, 2);
  ST_ACT_ALL(actw, 96, 3);
  __syncthreads();
  stagecpy<NT>(sh + 24576, wbuf + OFF_WS2, 8192, tid);
  __syncthreads();
  ACC_INIT(fl + 64);
  GEMM64(actw, 96, 3, sh + 24576, 2, 2);
  ST_ACT_ALL(actw, 96, 3);

  {
    float r0 = fl[320], r1 = fl[321], r2 = fl[322];
    for (int j = 0; j < 64; ++j) {
      float a = bf2f(actw[p * 96 + (j ^ ((p & 3) << 3))]);
      r0 = fmaf(a, fl[128 + 3 * j + 0], r0);
      r1 = fmaf(a, fl[128 + 3 * j + 1], r1);
      r2 = fmaf(a, fl[128 + 3 * j + 2], r2);
    }
    if (live) {
      out[3 * (size_t)n + 0] = mask ? sigmoidf_(r0) : 0.f;
      out[3 * (size_t)n + 1] = mask ? sigmoidf_(r1) : 0.f;
      out[3 * (size_t)n + 2] = mask ? sigmoidf_(r2) : 0.f;
    }
  }

  stp<96, 3>(actw, p, 0, hv0_.x, hv0_.y);   stp<96, 3>(actw, p, 2, hv0_.z, hv0_.w);
  stp<96, 3>(actw, p, 4, hv1_.x, hv1_.y);   stp<96, 3>(actw, p, 6, hv1_.z, hv1_.w);
  stp<96, 3>(actw, p, 8, hv2_.x, hv2_.y);   stp<96, 3>(actw, p, 10, hv2_.z, hv2_.w);
  stp<96, 3>(actw, p, 12, hv3_.x, hv3_.y);  stp<96, 3>(actw, p, 14, hv3_.z, hv3_.w);
  stp<96, 3>(actw, p, 16, et0.x, et0.y);    stp<96, 3>(actw, p, 18, et0.z, et0.w);
  stp<96, 3>(actw, p, 20, et1.x, et1.y);    stp<96, 3>(actw, p, 22, et1.z, et1.w);
  stp<96, 3>(actw, p, 24, et2.x, et2.y);    stp<96, 3>(actw, p, 26, et2.z, et2.w);
  stp<96, 3>(actw, p, 28, et3.x, et3.y);    stp<96, 3>(actw, p, 30, et3.z, et3.w);
  __syncthreads();
  stagecpy<NT>(sh + 24576, wbuf + OFF_WT1, 4096, tid);
  __syncthreads();
  ACC_INIT(fl + 384);
  GEMM64(actw, 96, 3, sh + 24576, 1, 2);
  ST_ACT_ALL(actw, 96, 3);
  __syncthreads();
  stagecpy<NT>(sh + 24576, wbuf + OFF_WT2, 8192, tid);
  __syncthreads();
  ACC_INIT(fl + 448);
  GEMM64(actw, 96, 3, sh + 24576, 2, 2);
  ST_ACT_ALL(actw, 96, 3);
  __syncthreads();
  stagecpy<NT>(sh + 24576, wbuf + OFF_WT3, 8192, tid);
  __syncthreads();
  ACC_INIT(fl + 512);
  GEMM64(actw, 96, 3, sh + 24576, 2, 2);
  ST_ACT_ALL(actw, 96, 3);

  float hd = fl[896], hr0 = fl[897], hr1 = fl[898], hr2 = fl[899], hb = fl[900];
  for (int j = 0; j < 64; ++j) {
    float a = bf2f(actw[p * 96 + (j ^ ((p & 3) << 3))]);
    hd = fmaf(a, fl[576 + j], hd);
    hr0 = fmaf(a, fl[640 + 3 * j + 0], hr0);
    hr1 = fmaf(a, fl[640 + 3 * j + 1], hr1);
    hr2 = fmaf(a, fl[640 + 3 * j + 2], hr2);
    hb = fmaf(a, fl[832 + j], hb);
  }
  if (live) {
    size_t N4 = (size_t)Npts * 4;
    out[N4 + 3 * (size_t)n + 0] = mask ? sigmoidf_(hr0) : 0.f;
    out[N4 + 3 * (size_t)n + 1] = mask ? sigmoidf_(hr1) : 0.f;
    out[N4 + 3 * (size_t)n + 2] = mask ? sigmoidf_(hr2) : 0.f;
    out[(size_t)Npts * 7 + n] = mask ? __expf(softplusf_(hd)) : 0.f;
    out[(size_t)Npts * 8 + n] = mask ? (softplusf_(hb) + 0.1f) : 0.1f;
  }
}

extern "C" void kernel_launch(void* const* d_in, const int* in_sizes, int n_in,
                              void* d_out, int out_size, void* d_ws, size_t ws_size,
                              hipStream_t stream) {
  const int Npts = in_sizes[0] / 3;
  const float* x = (const float*)d_in[0];
  const float* d = (const float*)d_in[1];
  const int* aidx = (const int*)d_in[2];
  const int* tridx = (const int*)d_in[3];
  const float* tables = (const float*)d_in[4];
  const float* emb_a = (const float*)d_in[5];
  const float* emb_t = (const float*)d_in[6];
  const float* Wd1 = (const float*)d_in[7];
  const float* bd1 = (const float*)d_in[8];
  const float* Wd2 = (const float*)d_in[9];
  const float* bd2 = (const float*)d_in[10];
  const float* Ws1 = (const float*)d_in[11];
  const float* bs1 = (const float*)d_in[12];
  const float* Ws2 = (const float*)d_in[13];
  const float* bs2 = (const float*)d_in[14];
  const float* Ws3 = (const float*)d_in[15];
  const float* bs3 = (const float*)d_in[16];
  const float* Wt1 = (const float*)d_in[17];
  const float* bt1 = (const float*)d_in[18];
  const float* Wt2 = (const float*)d_in[19];
  const float* bt2 = (const float*)d_in[20];
  const float* Wt3 = (const float*)d_in[21];
  const float* bt3 = (const float*)d_in[22];
  const float* Wtd = (const float*)d_in[23];
  const float* btd = (const float*)d_in[24];
  const float* Wtr = (const float*)d_in[25];
  const float* btr = (const float*)d_in[26];
  const float* Wtb = (const float*)d_in[27];
  const float* btb = (const float*)d_in[28];
  float* out = (float*)d_out;

  float* hvws = (float*)d_ws;
  const size_t hv_bytes = (size_t)Npts * 16 * sizeof(float);
  unsigned short* wbuf = (unsigned short*)((char*)d_ws + hv_bytes);
  unsigned short* t8 = (unsigned short*)((char*)d_ws + hv_bytes + WBUF_BYTES);
  const size_t t8_bytes = (size_t)16 * T_SIZE * 2;
  unsigned* featws = (unsigned*)((char*)d_ws + hv_bytes + WBUF_BYTES + t8_bytes);
  const size_t feat_bytes = (size_t)Npts * 64;
  const bool has_t8 = (ws_size >= hv_bytes + WBUF_BYTES + t8_bytes);
  const bool has_f = (ws_size >= hv_bytes + WBUF_BYTES + t8_bytes + feat_bytes);

  int blocksA = ((Npts + 255) / 256) * 4;
  int blocks0 = (Npts + NT0 - 1) / NT0;
  int blocks = (Npts + NT - 1) / NT;

  if (has_f) {
    int nq = (int)(16 * T_SIZE / 2);
    kprep<<<dim3(14 + (nq + 255) / 256), dim3(256), 0, stream>>>(
        tables, (unsigned*)t8, nq, Wd1, Wd2, Ws1, Ws2, Wt1, Wt2, Wt3, wbuf);
    k0a_gather<<<dim3(blocksA), dim3(256), 0, stream>>>(x, t8, featws, Npts);
    k12b_all<<<dim3(blocks), dim3(NT), 0, stream>>>(
        x, d, aidx, tridx, emb_a, emb_t, featws, wbuf,
        bd1, bd2, bs1, bs2, Ws3, bs3, bt1, bt2, bt3,
        Wtd, btd, Wtr, btr, Wtb, btb, out, Npts);
  } else {
    kwprep<<<dim3(14), dim3(256), 0, stream>>>(Wd1, Wd2, Ws1, Ws2, Wt1, Wt2, Wt3, wbuf);
    if (has_t8) {
      int nq = (int)(16 * T_SIZE / 2);
      kconv<<<dim3((nq + 255) / 256), dim3(256), 0, stream>>>(tables, (unsigned*)t8, nq);
      k0f_density<1><<<dim3(blocks0), dim3(NT0), 0, stream>>>(
          x, tables, t8, Wd1, bd1, Wd2, bd2, hvws, out, Npts);
    } else {
      k0f_density<0><<<dim3(blocks0), dim3(NT0), 0, stream>>>(
          x, tables, t8, Wd1, bd1, Wd2, bd2, hvws, out, Npts);
    }
    k12_heads<<<dim3(blocks), dim3(NT), 0, stream>>>(
        x, d, aidx, tridx, emb_a, emb_t, wbuf,
        bs1, bs2, Ws3, bs3, bt1, bt2, bt3,
        Wtd, btd, Wtr, btr, Wtb, btb, hvws, out, Npts);
  }
}

// Round 19
// 160.744 us; speedup vs baseline: 1.1728x; 1.1728x over previous
//
#include <hip/hip_runtime.h>
#include <hip/hip_fp16.h>
#include <math.h>

#define NT 256
#define NT0 512
#define T_SIZE 524288u
#define T_MASK 524287u
#define PR1 2654435761u
#define PR2 805459861u

// wbuf (pre-staged bf16 weight planes) layout, in ushort units
#define OFF_WD1 0
#define OFF_WD2 4096
#define OFF_WS1 6144
#define OFF_WS2 18432
#define OFF_WT1 26624
#define OFF_WT2 30720
#define OFF_WT3 38912
#define WBUF_USH 47104
#define WBUF_BYTES 98304

// act stride: 104 ushorts (208B = 52 dwords; 52%32=20 -> 8 consecutive rows
// land on 8 disjoint 4-bank spans = all 32 banks -> conflict-free b128 reads)
#define AS 104

typedef float f32x4 __attribute__((ext_vector_type(4)));
typedef short s16x8 __attribute__((ext_vector_type(8)));
typedef unsigned u32x4 __attribute__((ext_vector_type(4)));

__device__ __forceinline__ float sigmoidf_(float x) { return 1.0f / (1.0f + __expf(-x)); }
__device__ __forceinline__ float softplusf_(float x) { return fmaxf(x, 0.0f) + log1pf(__expf(-fabsf(x))); }

__device__ __forceinline__ unsigned short f2bf(float f) {
  union { float f; unsigned u; } v; v.f = f;
  unsigned r = v.u + 0x7fffu + ((v.u >> 16) & 1u);
  return (unsigned short)(r >> 16);
}
__device__ __forceinline__ float bf2f(unsigned short h) {
  union { unsigned u; float f; } v; v.u = ((unsigned)h) << 16; return v.f;
}
__device__ __forceinline__ f32x4 splat4(float t) { f32x4 v; v[0]=t; v[1]=t; v[2]=t; v[3]=t; return v; }

__device__ __forceinline__ unsigned char f2e5(float f) {
  unsigned short u = __half_as_ushort(__float2half(f));
  return (unsigned char)(((unsigned)u + 0x7Fu + ((u >> 8) & 1u)) >> 8);
}
__device__ __forceinline__ float e52f(unsigned v) {
  return __half2float(__ushort_as_half((unsigned short)((v & 0xFFu) << 8)));
}

template <int ASTR, int SWM>
__device__ __forceinline__ s16x8 lda(const unsigned short* act, int lane, int m, int kh) {
  int p = m * 16 + (lane & 15);
  int c = (kh * 32 + ((lane >> 4) << 3)) ^ ((p & SWM) << 3);
  return *reinterpret_cast<const s16x8*>(act + p * ASTR + c);
}
__device__ __forceinline__ s16x8 ldb(const unsigned short* wb, int lane, int fidx) {
  return *reinterpret_cast<const s16x8*>(wb + (fidx * 64 + lane) * 8);
}
template <int ASTR, int SWM>
__device__ __forceinline__ void stp(unsigned short* act, int p, int col, float v0, float v1) {
  unsigned pk = (unsigned)f2bf(v0) | (((unsigned)f2bf(v1)) << 16);
  *reinterpret_cast<unsigned*>(act + p * ASTR + (col ^ ((p & SWM) << 3))) = pk;
}

template <int BT, int KH, int NTI, int NCOLS, class F>
__device__ void stage_plane(unsigned short* dst, const float* __restrict__ W, int plane, int tid, F rowmap) {
  for (int i = tid; i < NTI * KH * 64; i += BT) {
    int f = i >> 6, lane = i & 63;
    int n = f / KH, kh = f - n * KH;
    int o = n * 16 + (lane & 15);
    int kb = kh * 32 + ((lane >> 4) << 3);
    unsigned us0, us1, us2, us3;
#define MKPAIR(dstu, j0) { \
      unsigned short e0, e1; \
      { int sr = rowmap(kb + (j0)); float w = (sr >= 0) ? W[sr * NCOLS + o] : 0.f; \
        unsigned short hi = f2bf(w); e0 = plane ? f2bf(w - bf2f(hi)) : hi; } \
      { int sr = rowmap(kb + (j0) + 1); float w = (sr >= 0) ? W[sr * NCOLS + o] : 0.f; \
        unsigned short hi = f2bf(w); e1 = plane ? f2bf(w - bf2f(hi)) : hi; } \
      dstu = (unsigned)e0 | (((unsigned)e1) << 16); }
    MKPAIR(us0, 0) MKPAIR(us1, 2) MKPAIR(us2, 4) MKPAIR(us3, 6)
#undef MKPAIR
    *reinterpret_cast<uint4*>(dst + (size_t)i * 8) = make_uint4(us0, us1, us2, us3);
  }
}

template <int BT>
__device__ __forceinline__ void stage(float* dst, const float* __restrict__ src, int cnt, int tid) {
  for (int i = tid; i < cnt; i += BT) dst[i] = src[i];
}

template <int BT>
__device__ __forceinline__ void stagecpy(unsigned short* dst, const unsigned short* __restrict__ src,
                                         int cnt_ush, int tid) {
  const uint4* s = reinterpret_cast<const uint4*>(src);
  uint4* d = reinterpret_cast<uint4*>(dst);
  for (int i = tid; i < (cnt_ush >> 3); i += BT) d[i] = s[i];
}

#define MFMA_(a, b, c) __builtin_amdgcn_mfma_f32_16x16x32_bf16(a, b, c, 0, 0, 0)

#define DECL_ACC f32x4 acc00, acc01, acc02, acc03, acc10, acc11, acc12, acc13, \
                       acc20, acc21, acc22, acc23, acc30, acc31, acc32, acc33;

#define ACC_INIT(B) { \
  float t0 = (B)[(lane & 15)], t1 = (B)[16 + (lane & 15)], t2 = (B)[32 + (lane & 15)], t3 = (B)[48 + (lane & 15)]; \
  acc00 = splat4(t0); acc10 = acc00; acc20 = acc00; acc30 = acc00; \
  acc01 = splat4(t1); acc11 = acc01; acc21 = acc01; acc31 = acc01; \
  acc02 = splat4(t2); acc12 = acc02; acc22 = acc02; acc32 = acc02; \
  acc03 = splat4(t3); acc13 = acc03; acc23 = acc03; acc33 = acc03; }

#define GEMM_NBLK(WPTR, kh, KH, n) { s16x8 b = ldb(WPTR, lane, (n) * (KH) + (kh)); \
  acc0##n = MFMA_(a0, b, acc0##n); acc1##n = MFMA_(a1, b, acc1##n); \
  acc2##n = MFMA_(a2, b, acc2##n); acc3##n = MFMA_(a3, b, acc3##n); }

#define GEMM64(ACTP, ASTR, SWM, WB, KH, PLN) { \
  _Pragma("unroll") for (int kh = 0; kh < (KH); ++kh) { \
    s16x8 a0 = lda<ASTR, SWM>(ACTP, lane, 0, kh), a1 = lda<ASTR, SWM>(ACTP, lane, 1, kh), \
          a2 = lda<ASTR, SWM>(ACTP, lane, 2, kh), a3 = lda<ASTR, SWM>(ACTP, lane, 3, kh); \
    _Pragma("unroll") for (int pl = 0; pl < (PLN); ++pl) { \
      const unsigned short* wp = (WB) + pl * (KH) * 2048; \
      GEMM_NBLK(wp, kh, KH, 0) GEMM_NBLK(wp, kh, KH, 1) GEMM_NBLK(wp, kh, KH, 2) GEMM_NBLK(wp, kh, KH, 3) } } }

#define ST_ACT1(ACTP, ASTR, SWM, m, n, A) { \
  _Pragma("unroll") for (int r = 0; r < 4; ++r) { \
    int p = (m) * 16 + ((lane >> 4) << 2) + r; int col = (n) * 16 + (lane & 15); \
    (ACTP)[p * (ASTR) + (col ^ ((p & (SWM)) << 3))] = f2bf(fmaxf((A)[r], 0.f)); } }

#define ST_ACT_ALL(ACTP, ASTR, SWM) \
  ST_ACT1(ACTP, ASTR, SWM, 0, 0, acc00) ST_ACT1(ACTP, ASTR, SWM, 0, 1, acc01) \
  ST_ACT1(ACTP, ASTR, SWM, 0, 2, acc02) ST_ACT1(ACTP, ASTR, SWM, 0, 3, acc03) \
  ST_ACT1(ACTP, ASTR, SWM, 1, 0, acc10) ST_ACT1(ACTP, ASTR, SWM, 1, 1, acc11) \
  ST_ACT1(ACTP, ASTR, SWM, 1, 2, acc12) ST_ACT1(ACTP, ASTR, SWM, 1, 3, acc13) \
  ST_ACT1(ACTP, ASTR, SWM, 2, 0, acc20) ST_ACT1(ACTP, ASTR, SWM, 2, 1, acc21) \
  ST_ACT1(ACTP, ASTR, SWM, 2, 2, acc22) ST_ACT1(ACTP, ASTR, SWM, 2, 3, acc23) \
  ST_ACT1(ACTP, ASTR, SWM, 3, 0, acc30) ST_ACT1(ACTP, ASTR, SWM, 3, 1, acc31) \
  ST_ACT1(ACTP, ASTR, SWM, 3, 2, acc32) ST_ACT1(ACTP, ASTR, SWM, 3, 3, acc33)

#define ST_HV(ACTP, ASTR, SWM, m, H) { \
  _Pragma("unroll") for (int r = 0; r < 4; ++r) { \
    int pp = (m) * 16 + ((lane >> 4) << 2) + r; \
    (ACTP)[pp * (ASTR) + ((lane & 15) ^ ((pp & (SWM)) << 3))] = f2bf((H)[r]); } }

// ============ wprep body (shared by kprep and legacy kwprep) ============
__device__ void wprep_block(int pid, int tid,
                            const float* Wd1, const float* Wd2, const float* Ws1,
                            const float* Ws2, const float* Wt1, const float* Wt2,
                            const float* Wt3, unsigned short* wbuf) {
  const float* W;
  int KH, NTI, NCOLS, mapt, dst;
  switch (pid >> 1) {
    case 0: W = Wd1; KH = 1; NTI = 4; NCOLS = 64; mapt = 0; dst = OFF_WD1 + (pid & 1) * 2048; break;
    case 1: W = Wd2; KH = 2; NTI = 1; NCOLS = 16; mapt = 0; dst = OFF_WD2 + (pid & 1) * 1024; break;
    case 2: W = Ws1; KH = 3; NTI = 4; NCOLS = 64; mapt = 1; dst = OFF_WS1 + (pid & 1) * 6144; break;
    case 3: W = Ws2; KH = 2; NTI = 4; NCOLS = 64; mapt = 0; dst = OFF_WS2 + (pid & 1) * 4096; break;
    case 4: W = Wt1; KH = 1; NTI = 4; NCOLS = 64; mapt = 0; dst = OFF_WT1 + (pid & 1) * 2048; break;
    case 5: W = Wt2; KH = 2; NTI = 4; NCOLS = 64; mapt = 0; dst = OFF_WT2 + (pid & 1) * 4096; break;
    default: W = Wt3; KH = 2; NTI = 4; NCOLS = 64; mapt = 0; dst = OFF_WT3 + (pid & 1) * 4096; break;
  }
  const int plane = pid & 1;
  const int total = NTI * KH * 64;
  for (int i = tid; i < total; i += 256) {
    int f = i >> 6, lane = i & 63;
    int n = f / KH, kh = f - n * KH;
    int o = n * 16 + (lane & 15);
    int kb = kh * 32 + ((lane >> 4) << 3);
    unsigned short e[8];
#pragma unroll
    for (int j = 0; j < 8; ++j) {
      int k = kb + j;
      int sr = mapt ? (k < 16 ? k : (k < 64 ? 27 + k : (k < 91 ? k - 48 : -1))) : k;
      float w = (sr >= 0) ? W[sr * NCOLS + o] : 0.f;
      unsigned short hi = f2bf(w);
      e[j] = plane ? f2bf(w - bf2f(hi)) : hi;
    }
    uint4 v;
    v.x = (unsigned)e[0] | ((unsigned)e[1] << 16);
    v.y = (unsigned)e[2] | ((unsigned)e[3] << 16);
    v.z = (unsigned)e[4] | ((unsigned)e[5] << 16);
    v.w = (unsigned)e[6] | ((unsigned)e[7] << 16);
    *reinterpret_cast<uint4*>(wbuf + dst + (size_t)i * 8) = v;
  }
}

// ============ Kprep: fused weight prep (blocks 0..13) + fp8 table conv ============
__global__ void __launch_bounds__(256) kprep(
    const float* __restrict__ tables, unsigned* __restrict__ t8, int nq,
    const float* __restrict__ Wd1, const float* __restrict__ Wd2,
    const float* __restrict__ Ws1, const float* __restrict__ Ws2,
    const float* __restrict__ Wt1, const float* __restrict__ Wt2,
    const float* __restrict__ Wt3, unsigned short* __restrict__ wbuf) {
  if (blockIdx.x < 14) {
    wprep_block(blockIdx.x, threadIdx.x, Wd1, Wd2, Ws1, Ws2, Wt1, Wt2, Wt3, wbuf);
    return;
  }
  int i = (blockIdx.x - 14) * 256 + threadIdx.x;
  if (i >= nq) return;
  f32x4 v = __builtin_nontemporal_load(reinterpret_cast<const f32x4*>(tables) + i);
  unsigned r = (unsigned)f2e5(v[0]) | ((unsigned)f2e5(v[1]) << 8) |
               ((unsigned)f2e5(v[2]) << 16) | ((unsigned)f2e5(v[3]) << 24);
  __builtin_nontemporal_store(r, t8 + i);
}

// ============ legacy kwprep / kconv (fallback path) ============
__global__ void __launch_bounds__(256) kwprep(
    const float* __restrict__ Wd1, const float* __restrict__ Wd2,
    const float* __restrict__ Ws1, const float* __restrict__ Ws2,
    const float* __restrict__ Wt1, const float* __restrict__ Wt2,
    const float* __restrict__ Wt3, unsigned short* __restrict__ wbuf) {
  wprep_block(blockIdx.x, threadIdx.x, Wd1, Wd2, Ws1, Ws2, Wt1, Wt2, Wt3, wbuf);
}
__global__ void __launch_bounds__(256) kconv(const float* __restrict__ tables,
                                             unsigned* __restrict__ t8, int nq) {
  int i = blockIdx.x * 256 + threadIdx.x;
  if (i >= nq) return;
  f32x4 v = __builtin_nontemporal_load(reinterpret_cast<const f32x4*>(tables) + i);
  unsigned r = (unsigned)f2e5(v[0]) | ((unsigned)f2e5(v[1]) << 8) |
               ((unsigned)f2e5(v[2]) << 16) | ((unsigned)f2e5(v[3]) << 24);
  __builtin_nontemporal_store(r, t8 + i);
}

// ============ K0a: hash gather, asm pipeline (round-17 form, reverted) ============
// Ledger: concurrency levers null (r15/r17), request-reduction negative (r12/r18),
// asm MLP pipeline captured (r14). ~0.7 lane-gathers/cyc/CU is the structural
// floor for random 2B gathers on this memory system.
__global__ void __launch_bounds__(256, 6) k0a_gather(
    const float* __restrict__ x, const unsigned short* __restrict__ t8,
    unsigned* __restrict__ featws, int Npts) {
  const int lane = threadIdx.x & 63, wv = threadIdx.x >> 6;
  const int g = blockIdx.x & 3;
  const int n = (blockIdx.x >> 2) * 256 + wv * 64 + lane;
  if (n >= Npts) return;
  float xn0 = x[3 * n + 0] * 0.25f + 0.5f;
  float xn1 = x[3 * n + 1] * 0.25f + 0.5f;
  float xn2 = x[3 * n + 2] * 0.25f + 0.5f;

  float scA, scB, scC, scD;
  switch (g) {
    case 0:  scA = 16.f; scB = 58.f;  scC = 213.f; scD = 777.f;  break;
    case 1:  scA = 22.f; scB = 80.f;  scC = 295.f; scD = 1074.f; break;
    case 2:  scA = 30.f; scB = 111.f; scC = 407.f; scD = 1483.f; break;
    default: scA = 42.f; scB = 154.f; scC = 563.f; scD = 2048.f; break;
  }

#define ALVL(J, SC) \
  unsigned ad##J##0, ad##J##1, ad##J##2, ad##J##3, ad##J##4, ad##J##5, ad##J##6, ad##J##7; \
  float lf##J##0, lf##J##1, lf##J##2; \
  { \
    float xs0 = xn0 * (SC), xs1 = xn1 * (SC), xs2 = xn2 * (SC); \
    float f0 = floorf(xs0), f1 = floorf(xs1), f2 = floorf(xs2); \
    lf##J##0 = xs0 - f0; lf##J##1 = xs1 - f1; lf##J##2 = xs2 - f2; \
    unsigned i0 = (unsigned)(int)f0, i1 = (unsigned)(int)f1, i2 = (unsigned)(int)f2; \
    unsigned a0 = i0, a1 = i0 + 1u; \
    unsigned b0 = i1 * PR1, b1 = (i1 + 1u) * PR1; \
    unsigned c0 = i2 * PR2, c1 = (i2 + 1u) * PR2; \
    unsigned base = (unsigned)(g + 4 * (J)) * T_SIZE; \
    ad##J##0 = (base + ((a0 ^ b0 ^ c0) & T_MASK)) * 2u; \
    ad##J##1 = (base + ((a1 ^ b0 ^ c0) & T_MASK)) * 2u; \
    ad##J##2 = (base + ((a0 ^ b1 ^ c0) & T_MASK)) * 2u; \
    ad##J##3 = (base + ((a1 ^ b1 ^ c0) & T_MASK)) * 2u; \
    ad##J##4 = (base + ((a0 ^ b0 ^ c1) & T_MASK)) * 2u; \
    ad##J##5 = (base + ((a1 ^ b0 ^ c1) & T_MASK)) * 2u; \
    ad##J##6 = (base + ((a0 ^ b1 ^ c1) & T_MASK)) * 2u; \
    ad##J##7 = (base + ((a1 ^ b1 ^ c1) & T_MASK)) * 2u; \
  }
  ALVL(0, scA) ALVL(1, scB) ALVL(2, scC) ALVL(3, scD)
#undef ALVL

#define GLD(Q, AD) asm volatile("global_load_ushort %0, %1, %2" : "=v"(Q) : "v"(AD), "s"(t8));
#define LLVL(J) \
  unsigned q##J##0, q##J##1, q##J##2, q##J##3, q##J##4, q##J##5, q##J##6, q##J##7; \
  GLD(q##J##0, ad##J##0) GLD(q##J##1, ad##J##1) GLD(q##J##2, ad##J##2) GLD(q##J##3, ad##J##3) \
  GLD(q##J##4, ad##J##4) GLD(q##J##5, ad##J##5) GLD(q##J##6, ad##J##6) GLD(q##J##7, ad##J##7)
  LLVL(0) LLVL(1) LLVL(2) LLVL(3)
#undef LLVL
#undef GLD

#define BLVL(J, FP) { \
    float w1x = lf##J##0, w0x = 1.f - w1x; \
    float w1y = lf##J##1, w0y = 1.f - w1y; \
    float w1z = lf##J##2, w0z = 1.f - w1z; \
    float w000 = w0x * w0y * w0z, w100 = w1x * w0y * w0z; \
    float w010 = w0x * w1y * w0z, w110 = w1x * w1y * w0z; \
    float w001 = w0x * w0y * w1z, w101 = w1x * w0y * w1z; \
    float w011 = w0x * w1y * w1z, w111 = w1x * w1y * w1z; \
    float fa = w000 * e52f(q##J##0) + w100 * e52f(q##J##1) + w010 * e52f(q##J##2) + \
               w110 * e52f(q##J##3) + w001 * e52f(q##J##4) + w101 * e52f(q##J##5) + \
               w011 * e52f(q##J##6) + w111 * e52f(q##J##7); \
    float fb = w000 * e52f(q##J##0 >> 8) + w100 * e52f(q##J##1 >> 8) + w010 * e52f(q##J##2 >> 8) + \
               w110 * e52f(q##J##3 >> 8) + w001 * e52f(q##J##4 >> 8) + w101 * e52f(q##J##5 >> 8) + \
               w011 * e52f(q##J##6 >> 8) + w111 * e52f(q##J##7 >> 8); \
    FP = (unsigned)f2bf(fa) | (((unsigned)f2bf(fb)) << 16); }
  unsigned fp0, fp1, fp2, fp3;
  asm volatile("s_waitcnt vmcnt(24)" ::: "memory");
  __builtin_amdgcn_sched_barrier(0);
  BLVL(0, fp0)
  asm volatile("s_waitcnt vmcnt(16)" ::: "memory");
  __builtin_amdgcn_sched_barrier(0);
  BLVL(1, fp1)
  asm volatile("s_waitcnt vmcnt(8)" ::: "memory");
  __builtin_amdgcn_sched_barrier(0);
  BLVL(2, fp2)
  asm volatile("s_waitcnt vmcnt(0)" ::: "memory");
  __builtin_amdgcn_sched_barrier(0);
  BLVL(3, fp3)
#undef BLVL
  u32x4 o; o[0] = fp0; o[1] = fp1; o[2] = fp2; o[3] = fp3;
  __builtin_nontemporal_store(
      o, reinterpret_cast<u32x4*>(featws + ((size_t)g * Npts + n) * 4));
}

// ============ K12b: fused density + static + transient (stride-104 acts) ============
__global__ void __launch_bounds__(NT, 2) k12b_all(
    const float* __restrict__ x, const float* __restrict__ d,
    const int* __restrict__ aidx, const int* __restrict__ tridx,
    const float* __restrict__ emb_a, const float* __restrict__ emb_t,
    const unsigned* __restrict__ featws, const unsigned short* __restrict__ wbuf,
    const float* __restrict__ bd1, const float* __restrict__ bd2,
    const float* __restrict__ bs1, const float* __restrict__ bs2,
    const float* __restrict__ Ws3, const float* __restrict__ bs3,
    const float* __restrict__ bt1, const float* __restrict__ bt2,
    const float* __restrict__ bt3,
    const float* __restrict__ Wtd, const float* __restrict__ btd,
    const float* __restrict__ Wtr, const float* __restrict__ btr,
    const float* __restrict__ Wtb, const float* __restrict__ btb,
    float* __restrict__ out, int Npts) {
  __shared__ __align__(16) unsigned short sh[38912];  // acts 4x64x104=26624 | wreg 12288
  __shared__ __align__(16) float fl[984];
  const int tid = threadIdx.x, lane = tid & 63, wv = tid >> 6;
  const int n = blockIdx.x * NT + tid;
  const bool live = (n < Npts);
  const int nn = live ? n : Npts - 1;
  unsigned short* actw = sh + wv * (64 * AS);
  unsigned short* wreg = sh + 26624;
  float* exch = reinterpret_cast<float*>(wreg + 6144);
  const int p = lane;

  float xn0 = x[3 * nn + 0] * 0.25f, xn1 = x[3 * nn + 1] * 0.25f, xn2 = x[3 * nn + 2] * 0.25f;
  const bool mask = (fabsf(xn0) < 0.5f) && (fabsf(xn1) < 0.5f) && (fabsf(xn2) < 0.5f);

  u32x4 q0 = __builtin_nontemporal_load(
      reinterpret_cast<const u32x4*>(featws + ((size_t)0 * Npts + nn) * 4));
  u32x4 q1 = __builtin_nontemporal_load(
      reinterpret_cast<const u32x4*>(featws + ((size_t)1 * Npts + nn) * 4));
  u32x4 q2 = __builtin_nontemporal_load(
      reinterpret_cast<const u32x4*>(featws + ((size_t)2 * Npts + nn) * 4));
  u32x4 q3 = __builtin_nontemporal_load(
      reinterpret_cast<const u32x4*>(featws + ((size_t)3 * Npts + nn) * 4));
  const float4* tp = reinterpret_cast<const float4*>(emb_t + (size_t)tridx[nn] * 16);
  float4 et0 = tp[0], et1 = tp[1], et2 = tp[2], et3 = tp[3];

  {
    float d0 = d[3 * nn + 0], d1 = d[3 * nn + 1], d2 = d[3 * nn + 2];
    float s10 = __sinf(d0), s11 = __sinf(d1), s12 = __sinf(d2);
    float c10 = __cosf(d0), c11 = __cosf(d1), c12 = __cosf(d2);
    float s20 = __sinf(2.f * d0), s21 = __sinf(2.f * d1), s22 = __sinf(2.f * d2);
    float c20 = __cosf(2.f * d0), c21 = __cosf(2.f * d1), c22 = __cosf(2.f * d2);
    float s40 = __sinf(4.f * d0), s41 = __sinf(4.f * d1), s42 = __sinf(4.f * d2);
    float c40 = __cosf(4.f * d0), c41 = __cosf(4.f * d1), c42 = __cosf(4.f * d2);
    float s80 = __sinf(8.f * d0), s81 = __sinf(8.f * d1), s82 = __sinf(8.f * d2);
    float c80 = __cosf(8.f * d0), c81 = __cosf(8.f * d1), c82 = __cosf(8.f * d2);
    stp<AS, 0>(actw, p, 64, d0, d1);   stp<AS, 0>(actw, p, 66, d2, s10);
    stp<AS, 0>(actw, p, 68, s11, s12); stp<AS, 0>(actw, p, 70, c10, c11);
    stp<AS, 0>(actw, p, 72, c12, s20); stp<AS, 0>(actw, p, 74, s21, s22);
    stp<AS, 0>(actw, p, 76, c20, c21); stp<AS, 0>(actw, p, 78, c22, s40);
    stp<AS, 0>(actw, p, 80, s41, s42); stp<AS, 0>(actw, p, 82, c40, c41);
    stp<AS, 0>(actw, p, 84, c42, s80); stp<AS, 0>(actw, p, 86, s81, s82);
    stp<AS, 0>(actw, p, 88, c80, c81); stp<AS, 0>(actw, p, 90, c82, 0.f);
    stp<AS, 0>(actw, p, 92, 0.f, 0.f); stp<AS, 0>(actw, p, 94, 0.f, 0.f);
  }
#define PUTL(l, val) *reinterpret_cast<unsigned*>(actw + p * AS + 2 * (l)) = (val);
  PUTL(0, q0[0]) PUTL(4, q0[1]) PUTL(8, q0[2]) PUTL(12, q0[3])
  PUTL(1, q1[0]) PUTL(5, q1[1]) PUTL(9, q1[2]) PUTL(13, q1[3])
  PUTL(2, q2[0]) PUTL(6, q2[1]) PUTL(10, q2[2]) PUTL(14, q2[3])
  PUTL(3, q3[0]) PUTL(7, q3[1]) PUTL(11, q3[2]) PUTL(15, q3[3])
#undef PUTL

  stagecpy<NT>(wreg, wbuf + OFF_WD1, 4096, tid);
  stagecpy<NT>(wreg + 4096, wbuf + OFF_WD2, 2048, tid);
  stage<NT>(fl, bs1, 64, tid);
  stage<NT>(fl + 64, bs2, 64, tid);
  stage<NT>(fl + 128, Ws3, 192, tid);
  if (tid < 3) fl[320 + tid] = bs3[tid];
  stage<NT>(fl + 384, bt1, 64, tid);
  stage<NT>(fl + 448, bt2, 64, tid);
  stage<NT>(fl + 512, bt3, 64, tid);
  stage<NT>(fl + 576, Wtd, 64, tid);
  stage<NT>(fl + 640, Wtr, 192, tid);
  stage<NT>(fl + 832, Wtb, 64, tid);
  if (tid == 0) { fl[896] = btd[0]; fl[900] = btb[0]; }
  if (tid < 3) fl[897 + tid] = btr[tid];
  stage<NT>(fl + 904, bd1, 64, tid);
  stage<NT>(fl + 968, bd2, 16, tid);
  __syncthreads();

  // ---- density ----
  DECL_ACC;
  ACC_INIT(fl + 904);
  GEMM64(actw, AS, 0, wreg, 1, 2);
  ST_ACT_ALL(actw, AS, 0);

  f32x4 h0, h1, h2, h3;
  { float t = fl[968 + (lane & 15)]; h0 = splat4(t); h1 = h0; h2 = h0; h3 = h0; }
#pragma unroll
  for (int kh = 0; kh < 2; ++kh) {
    s16x8 a0 = lda<AS, 0>(actw, lane, 0, kh), a1 = lda<AS, 0>(actw, lane, 1, kh),
          a2 = lda<AS, 0>(actw, lane, 2, kh), a3 = lda<AS, 0>(actw, lane, 3, kh);
#pragma unroll
    for (int pl = 0; pl < 2; ++pl) {
      s16x8 b = ldb(wreg + 4096 + pl * 1024, lane, kh);
      h0 = MFMA_(a0, b, h0); h1 = MFMA_(a1, b, h1); h2 = MFMA_(a2, b, h2); h3 = MFMA_(a3, b, h3);
    }
  }
#define HV_X(m, H) { _Pragma("unroll") for (int r = 0; r < 4; ++r) { \
    int pr = (m) * 16 + ((lane >> 4) << 2) + r; \
    if ((lane & 15) == 0) exch[wv * 64 + pr] = (H)[r]; } }
  HV_X(0, h0) HV_X(1, h1) HV_X(2, h2) HV_X(3, h3)
#undef HV_X
  ST_HV(actw, AS, 0, 0, h0) ST_HV(actw, AS, 0, 1, h1)
  ST_HV(actw, AS, 0, 2, h2) ST_HV(actw, AS, 0, 3, h3)
  {
    float hv0v = exch[wv * 64 + lane];
    if (live) out[3 * (size_t)Npts + n] = mask ? __expf(hv0v) : 0.f;
  }
  {
    const float4* ap = reinterpret_cast<const float4*>(emb_a + (size_t)aidx[nn] * 48);
#pragma unroll
    for (int q = 0; q < 12; ++q) {
      float4 e = ap[q];
      stp<AS, 0>(actw, p, 16 + 4 * q, e.x, e.y);
      stp<AS, 0>(actw, p, 18 + 4 * q, e.z, e.w);
    }
  }
  __syncthreads();
  stagecpy<NT>(wreg, wbuf + OFF_WS1, 12288, tid);
  __syncthreads();

  // ---- static head ----
  ACC_INIT(fl);
  GEMM64(actw, AS, 0, wreg, 3, 2);
  ST_ACT_ALL(actw, AS, 0);
  __syncthreads();
  stagecpy<NT>(wreg, wbuf + OFF_WS2, 8192, tid);
  __syncthreads();
  ACC_INIT(fl + 64);
  GEMM64(actw, AS, 0, wreg, 2, 2);
  ST_ACT_ALL(actw, AS, 0);

  {
    float r0 = fl[320], r1 = fl[321], r2 = fl[322];
    for (int j = 0; j < 64; ++j) {
      int jj = (j + 2 * p) & 63;
      float a = bf2f(actw[p * AS + jj]);
      r0 = fmaf(a, fl[128 + 3 * jj + 0], r0);
      r1 = fmaf(a, fl[128 + 3 * jj + 1], r1);
      r2 = fmaf(a, fl[128 + 3 * jj + 2], r2);
    }
    if (live) {
      out[3 * (size_t)n + 0] = mask ? sigmoidf_(r0) : 0.f;
      out[3 * (size_t)n + 1] = mask ? sigmoidf_(r1) : 0.f;
      out[3 * (size_t)n + 2] = mask ? sigmoidf_(r2) : 0.f;
    }
  }

  // ---- transient ----
  ST_HV(actw, AS, 0, 0, h0) ST_HV(actw, AS, 0, 1, h1)
  ST_HV(actw, AS, 0, 2, h2) ST_HV(actw, AS, 0, 3, h3)
  stp<AS, 0>(actw, p, 16, et0.x, et0.y);  stp<AS, 0>(actw, p, 18, et0.z, et0.w);
  stp<AS, 0>(actw, p, 20, et1.x, et1.y);  stp<AS, 0>(actw, p, 22, et1.z, et1.w);
  stp<AS, 0>(actw, p, 24, et2.x, et2.y);  stp<AS, 0>(actw, p, 26, et2.z, et2.w);
  stp<AS, 0>(actw, p, 28, et3.x, et3.y);  stp<AS, 0>(actw, p, 30, et3.z, et3.w);
  __syncthreads();
  stagecpy<NT>(wreg, wbuf + OFF_WT1, 4096, tid);
  stagecpy<NT>(wreg + 4096, wbuf + OFF_WT2, 8192, tid);
  __syncthreads();
  ACC_INIT(fl + 384);
  GEMM64(actw, AS, 0, wreg, 1, 2);
  ST_ACT_ALL(actw, AS, 0);
  ACC_INIT(fl + 448);
  GEMM64(actw, AS, 0, (wreg + 4096), 2, 2);
  ST_ACT_ALL(actw, AS, 0);
  __syncthreads();
  stagecpy<NT>(wreg, wbuf + OFF_WT3, 8192, tid);
  __syncthreads();
  ACC_INIT(fl + 512);
  GEMM64(actw, AS, 0, wreg, 2, 2);
  ST_ACT_ALL(actw, AS, 0);

  float hd = fl[896], hr0 = fl[897], hr1 = fl[898], hr2 = fl[899], hb = fl[900];
  for (int j = 0; j < 64; ++j) {
    int jj = (j + 2 * p) & 63;
    float a = bf2f(actw[p * AS + jj]);
    hd = fmaf(a, fl[576 + jj], hd);
    hr0 = fmaf(a, fl[640 + 3 * jj + 0], hr0);
    hr1 = fmaf(a, fl[640 + 3 * jj + 1], hr1);
    hr2 = fmaf(a, fl[640 + 3 * jj + 2], hr2);
    hb = fmaf(a, fl[832 + jj], hb);
  }
  if (live) {
    size_t N4 = (size_t)Npts * 4;
    out[N4 + 3 * (size_t)n + 0] = mask ? sigmoidf_(hr0) : 0.f;
    out[N4 + 3 * (size_t)n + 1] = mask ? sigmoidf_(hr1) : 0.f;
    out[N4 + 3 * (size_t)n + 2] = mask ? sigmoidf_(hr2) : 0.f;
    out[(size_t)Npts * 7 + n] = mask ? __expf(softplusf_(hd)) : 0.f;
    out[(size_t)Npts * 8 + n] = mask ? (softplusf_(hb) + 0.1f) : 0.1f;
  }
}

// ============ K0f: fused fallback (self-staging, writes hvws) ============
template <int F8>
__global__ void __launch_bounds__(NT0, 4) k0f_density(
    const float* __restrict__ x, const float* __restrict__ tables,
    const unsigned short* __restrict__ t8,
    const float* __restrict__ Wd1, const float* __restrict__ bd1,
    const float* __restrict__ Wd2, const float* __restrict__ bd2,
    float* __restrict__ hvws, float* __restrict__ out, int Npts) {
  __shared__ __align__(16) unsigned short sh[38912];
  __shared__ __align__(16) float fl[592];
  const int tid = threadIdx.x, lane = tid & 63, wv = tid >> 6;
  const int n = blockIdx.x * NT0 + tid;
  const bool live = (n < Npts);
  const int nn = live ? n : Npts - 1;

  stage_plane<NT0, 1, 4, 64>(sh + 32768, Wd1, 0, tid, [](int k) { return k; });
  stage_plane<NT0, 1, 4, 64>(sh + 32768 + 2048, Wd1, 1, tid, [](int k) { return k; });
  stage_plane<NT0, 2, 1, 16>(sh + 36864, Wd2, 0, tid, [](int k) { return k; });
  stage_plane<NT0, 2, 1, 16>(sh + 36864 + 1024, Wd2, 1, tid, [](int k) { return k; });
  stage<NT0>(fl, bd1, 64, tid);
  stage<NT0>(fl + 64, bd2, 16, tid);
  __syncthreads();

  unsigned short* actw = sh + wv * 4096;
  const int p = lane;
  float xn0 = x[3 * nn + 0] * 0.25f + 0.5f, xn1 = x[3 * nn + 1] * 0.25f + 0.5f, xn2 = x[3 * nn + 2] * 0.25f + 0.5f;
  const bool mask = (fabsf(xn0 - 0.5f) < 0.5f) && (fabsf(xn1 - 0.5f) < 0.5f) && (fabsf(xn2 - 0.5f) < 0.5f);

  const float2* tab2 = reinterpret_cast<const float2*>(tables);
  constexpr float NLV[16] = {16.f, 22.f, 30.f, 42.f, 58.f, 80.f, 111.f, 154.f,
                             213.f, 295.f, 407.f, 563.f, 777.f, 1074.f, 1483.f, 2048.f};
#pragma unroll
  for (int l = 0; l < 16; ++l) {
    const float sc = NLV[l];
    float xs0 = xn0 * sc, xs1 = xn1 * sc, xs2 = xn2 * sc;
    float f0 = floorf(xs0), f1 = floorf(xs1), f2 = floorf(xs2);
    float l0 = xs0 - f0, l1 = xs1 - f1, l2 = xs2 - f2;
    unsigned i0 = (unsigned)(int)f0, i1 = (unsigned)(int)f1, i2 = (unsigned)(int)f2;
    unsigned a0 = i0, a1 = i0 + 1u;
    unsigned b0 = i1 * PR1, b1 = (i1 + 1u) * PR1;
    unsigned c0 = i2 * PR2, c1 = (i2 + 1u) * PR2;
    float w0x = 1.f - l0, w1x = l0, w0y = 1.f - l1, w1y = l1, w0z = 1.f - l2, w1z = l2;
    float2 t0, t1, t2, t3, t4, t5, t6, t7;
    if constexpr (F8) {
      const unsigned short* tl8 = t8 + (size_t)l * T_SIZE;
      unsigned short q0 = tl8[(a0 ^ b0 ^ c0) & T_MASK];
      unsigned short q1 = tl8[(a1 ^ b0 ^ c0) & T_MASK];
      unsigned short q2 = tl8[(a0 ^ b1 ^ c0) & T_MASK];
      unsigned short q3 = tl8[(a1 ^ b1 ^ c0) & T_MASK];
      unsigned short q4 = tl8[(a0 ^ b0 ^ c1) & T_MASK];
      unsigned short q5 = tl8[(a1 ^ b0 ^ c1) & T_MASK];
      unsigned short q6 = tl8[(a0 ^ b1 ^ c1) & T_MASK];
      unsigned short q7 = tl8[(a1 ^ b1 ^ c1) & T_MASK];
      t0 = make_float2(e52f(q0), e52f(q0 >> 8));
      t1 = make_float2(e52f(q1), e52f(q1 >> 8));
      t2 = make_float2(e52f(q2), e52f(q2 >> 8));
      t3 = make_float2(e52f(q3), e52f(q3 >> 8));
      t4 = make_float2(e52f(q4), e52f(q4 >> 8));
      t5 = make_float2(e52f(q5), e52f(q5 >> 8));
      t6 = make_float2(e52f(q6), e52f(q6 >> 8));
      t7 = make_float2(e52f(q7), e52f(q7 >> 8));
    } else {
      const float2* tl = tab2 + (size_t)l * T_SIZE;
      t0 = tl[(a0 ^ b0 ^ c0) & T_MASK];
      t1 = tl[(a1 ^ b0 ^ c0) & T_MASK];
      t2 = tl[(a0 ^ b1 ^ c0) & T_MASK];
      t3 = tl[(a1 ^ b1 ^ c0) & T_MASK];
      t4 = tl[(a0 ^ b0 ^ c1) & T_MASK];
      t5 = tl[(a1 ^ b0 ^ c1) & T_MASK];
      t6 = tl[(a0 ^ b1 ^ c1) & T_MASK];
      t7 = tl[(a1 ^ b1 ^ c1) & T_MASK];
    }
    float w000 = w0x * w0y * w0z, w100 = w1x * w0y * w0z;
    float w010 = w0x * w1y * w0z, w110 = w1x * w1y * w0z;
    float w001 = w0x * w0y * w1z, w101 = w1x * w0y * w1z;
    float w011 = w0x * w1y * w1z, w111 = w1x * w1y * w1z;
    float fa = w000 * t0.x + w100 * t1.x + w010 * t2.x + w110 * t3.x +
               w001 * t4.x + w101 * t5.x + w011 * t6.x + w111 * t7.x;
    float fb = w000 * t0.y + w100 * t1.y + w010 * t2.y + w110 * t3.y +
               w001 * t4.y + w101 * t5.y + w011 * t6.y + w111 * t7.y;
    unsigned pk = (unsigned)f2bf(fa) | (((unsigned)f2bf(fb)) << 16);
    *reinterpret_cast<unsigned*>(actw + p * 64 + ((2 * l) ^ ((p & 7) << 3))) = pk;
  }

  DECL_ACC;
  ACC_INIT(fl);
  GEMM64(actw, 64, 7, sh + 32768, 1, 2);
  ST_ACT_ALL(actw, 64, 7);

  f32x4 h0, h1, h2, h3;
  { float t = fl[64 + (lane & 15)]; h0 = splat4(t); h1 = h0; h2 = h0; h3 = h0; }
  {
#pragma unroll
    for (int kh = 0; kh < 2; ++kh) {
      s16x8 a0 = lda<64, 7>(actw, lane, 0, kh), a1 = lda<64, 7>(actw, lane, 1, kh),
            a2 = lda<64, 7>(actw, lane, 2, kh), a3 = lda<64, 7>(actw, lane, 3, kh);
#pragma unroll
      for (int pl = 0; pl < 2; ++pl) {
        s16x8 b = ldb(sh + 36864 + pl * 1024, lane, kh);
        h0 = MFMA_(a0, b, h0); h1 = MFMA_(a1, b, h1); h2 = MFMA_(a2, b, h2); h3 = MFMA_(a3, b, h3);
      }
    }
  }
  const int ptbase = blockIdx.x * NT0 + wv * 64;
#define HV_ST(m, H) { _Pragma("unroll") for (int r = 0; r < 4; ++r) { \
    int pr = (m) * 16 + ((lane >> 4) << 2) + r; \
    if (ptbase + pr < Npts) hvws[(size_t)(ptbase + pr) * 16 + (lane & 15)] = (H)[r]; \
    if ((lane & 15) == 0) fl[80 + wv * 64 + pr] = (H)[r]; } }
  HV_ST(0, h0) HV_ST(1, h1) HV_ST(2, h2) HV_ST(3, h3)
#undef HV_ST
  float hv0 = fl[80 + wv * 64 + lane];
  if (live) out[3 * (size_t)Npts + n] = mask ? __expf(hv0) : 0.f;
}

// ============ K12 legacy (fallback path, reads hvws) ============
__global__ void __launch_bounds__(NT, 2) k12_heads(
    const float* __restrict__ x, const float* __restrict__ d,
    const int* __restrict__ aidx, const int* __restrict__ tridx,
    const float* __restrict__ emb_a, const float* __restrict__ emb_t,
    const unsigned short* __restrict__ wbuf,
    const float* __restrict__ bs1, const float* __restrict__ bs2,
    const float* __restrict__ Ws3, const float* __restrict__ bs3,
    const float* __restrict__ bt1, const float* __restrict__ bt2,
    const float* __restrict__ bt3,
    const float* __restrict__ Wtd, const float* __restrict__ btd,
    const float* __restrict__ Wtr, const float* __restrict__ btr,
    const float* __restrict__ Wtb, const float* __restrict__ btb,
    const float* __restrict__ hvws, float* __restrict__ out, int Npts) {
  __shared__ __align__(16) unsigned short sh[36864];
  __shared__ __align__(16) float fl[904];
  const int tid = threadIdx.x, lane = tid & 63, wv = tid >> 6;
  const int n = blockIdx.x * NT + tid;
  const bool live = (n < Npts);
  const int nn = live ? n : Npts - 1;
  unsigned short* actw = sh + wv * 6144;
  const int p = lane;

  float xn0 = x[3 * nn + 0] * 0.25f, xn1 = x[3 * nn + 1] * 0.25f, xn2 = x[3 * nn + 2] * 0.25f;
  const bool mask = (fabsf(xn0) < 0.5f) && (fabsf(xn1) < 0.5f) && (fabsf(xn2) < 0.5f);

  const float4* hvp = reinterpret_cast<const float4*>(hvws + (size_t)nn * 16);
  float4 hv0_ = hvp[0], hv1_ = hvp[1], hv2_ = hvp[2], hv3_ = hvp[3];
  const float4* tp = reinterpret_cast<const float4*>(emb_t + (size_t)tridx[nn] * 16);
  float4 et0 = tp[0], et1 = tp[1], et2 = tp[2], et3 = tp[3];

  {
    stp<96, 3>(actw, p, 0, hv0_.x, hv0_.y);   stp<96, 3>(actw, p, 2, hv0_.z, hv0_.w);
    stp<96, 3>(actw, p, 4, hv1_.x, hv1_.y);   stp<96, 3>(actw, p, 6, hv1_.z, hv1_.w);
    stp<96, 3>(actw, p, 8, hv2_.x, hv2_.y);   stp<96, 3>(actw, p, 10, hv2_.z, hv2_.w);
    stp<96, 3>(actw, p, 12, hv3_.x, hv3_.y);  stp<96, 3>(actw, p, 14, hv3_.z, hv3_.w);
    const float4* ap = reinterpret_cast<const float4*>(emb_a + (size_t)aidx[nn] * 48);
#pragma unroll
    for (int q = 0; q < 12; ++q) {
      float4 e = ap[q];
      stp<96, 3>(actw, p, 16 + 4 * q, e.x, e.y);
      stp<96, 3>(actw, p, 18 + 4 * q, e.z, e.w);
    }
    float d0 = d[3 * nn + 0], d1 = d[3 * nn + 1], d2 = d[3 * nn + 2];
    float s10 = __sinf(d0), s11 = __sinf(d1), s12 = __sinf(d2);
    float c10 = __cosf(d0), c11 = __cosf(d1), c12 = __cosf(d2);
    float s20 = __sinf(2.f * d0), s21 = __sinf(2.f * d1), s22 = __sinf(2.f * d2);
    float c20 = __cosf(2.f * d0), c21 = __cosf(2.f * d1), c22 = __cosf(2.f * d2);
    float s40 = __sinf(4.f * d0), s41 = __sinf(4.f * d1), s42 = __sinf(4.f * d2);
    float c40 = __cosf(4.f * d0), c41 = __cosf(4.f * d1), c42 = __cosf(4.f * d2);
    float s80 = __sinf(8.f * d0), s81 = __sinf(8.f * d1), s82 = __sinf(8.f * d2);
    float c80 = __cosf(8.f * d0), c81 = __cosf(8.f * d1), c82 = __cosf(8.f * d2);
    stp<96, 3>(actw, p, 64, d0, d1);   stp<96, 3>(actw, p, 66, d2, s10);
    stp<96, 3>(actw, p, 68, s11, s12); stp<96, 3>(actw, p, 70, c10, c11);
    stp<96, 3>(actw, p, 72, c12, s20); stp<96, 3>(actw, p, 74, s21, s22);
    stp<96, 3>(actw, p, 76, c20, c21); stp<96, 3>(actw, p, 78, c22, s40);
    stp<96, 3>(actw, p, 80, s41, s42); stp<96, 3>(actw, p, 82, c40, c41);
    stp<96, 3>(actw, p, 84, c42, s80); stp<96, 3>(actw, p, 86, s81, s82);
    stp<96, 3>(actw, p, 88, c80, c81); stp<96, 3>(actw, p, 90, c82, 0.f);
    stp<96, 3>(actw, p, 92, 0.f, 0.f); stp<96, 3>(actw, p, 94, 0.f, 0.f);
  }
  stagecpy<NT>(sh + 24576, wbuf + OFF_WS1, 12288, tid);
  stage<NT>(fl, bs1, 64, tid);
  stage<NT>(fl + 64, bs2, 64, tid);
  stage<NT>(fl + 128, Ws3, 192, tid);
  if (tid < 3) fl[320 + tid] = bs3[tid];
  stage<NT>(fl + 384, bt1, 64, tid);
  stage<NT>(fl + 448, bt2, 64, tid);
  stage<NT>(fl + 512, bt3, 64, tid);
  stage<NT>(fl + 576, Wtd, 64, tid);
  stage<NT>(fl + 640, Wtr, 192, tid);
  stage<NT>(fl + 832, Wtb, 64, tid);
  if (tid == 0) { fl[896] = btd[0]; fl[900] = btb[0]; }
  if (tid < 3) fl[897 + tid] = btr[tid];
  __syncthreads();

  DECL_ACC;
  ACC_INIT(fl);
  GEMM64(actw, 96, 3, sh + 24576, 3, 2);
  ST_ACT_ALL(actw, 96, 3);
  __syncthreads();
  stagecpy<NT>(sh + 24576, wbuf + OFF_WS2, 8192, tid);
  __syncthreads();
  ACC_INIT(fl + 64);
  GEMM64(actw, 96, 3, sh + 24576, 2, 2);
  ST_ACT_ALL(actw, 96, 3);

  {
    float r0 = fl[320], r1 = fl[321], r2 = fl[322];
    for (int j = 0; j < 64; ++j) {
      float a = bf2f(actw[p * 96 + (j ^ ((p & 3) << 3))]);
      r0 = fmaf(a, fl[128 + 3 * j + 0], r0);
      r1 = fmaf(a, fl[128 + 3 * j + 1], r1);
      r2 = fmaf(a, fl[128 + 3 * j + 2], r2);
    }
    if (live) {
      out[3 * (size_t)n + 0] = mask ? sigmoidf_(r0) : 0.f;
      out[3 * (size_t)n + 1] = mask ? sigmoidf_(r1) : 0.f;
      out[3 * (size_t)n + 2] = mask ? sigmoidf_(r2) : 0.f;
    }
  }

  stp<96, 3>(actw, p, 0, hv0_.x, hv0_.y);   stp<96, 3>(actw, p, 2, hv0_.z, hv0_.w);
  stp<96, 3>(actw, p, 4, hv1_.x, hv1_.y);   stp<96, 3>(actw, p, 6, hv1_.z, hv1_.w);
  stp<96, 3>(actw, p, 8, hv2_.x, hv2_.y);   stp<96, 3>(actw, p, 10, hv2_.z, hv2_.w);
  stp<96, 3>(actw, p, 12, hv3_.x, hv3_.y);  stp<96, 3>(actw, p, 14, hv3_.z, hv3_.w);
  stp<96, 3>(actw, p, 16, et0.x, et0.y);    stp<96, 3>(actw, p, 18, et0.z, et0.w);
  stp<96, 3>(actw, p, 20, et1.x, et1.y);    stp<96, 3>(actw, p, 22, et1.z, et1.w);
  stp<96, 3>(actw, p, 24, et2.x, et2.y);    stp<96, 3>(actw, p, 26, et2.z, et2.w);
  stp<96, 3>(actw, p, 28, et3.x, et3.y);    stp<96, 3>(actw, p, 30, et3.z, et3.w);
  __syncthreads();
  stagecpy<NT>(sh + 24576, wbuf + OFF_WT1, 4096, tid);
  __syncthreads();
  ACC_INIT(fl + 384);
  GEMM64(actw, 96, 3, sh + 24576, 1, 2);
  ST_ACT_ALL(actw, 96, 3);
  __syncthreads();
  stagecpy<NT>(sh + 24576, wbuf + OFF_WT2, 8192, tid);
  __syncthreads();
  ACC_INIT(fl + 448);
  GEMM64(actw, 96, 3, sh + 24576, 2, 2);
  ST_ACT_ALL(actw, 96, 3);
  __syncthreads();
  stagecpy<NT>(sh + 24576, wbuf + OFF_WT3, 8192, tid);
  __syncthreads();
  ACC_INIT(fl + 512);
  GEMM64(actw, 96, 3, sh + 24576, 2, 2);
  ST_ACT_ALL(actw, 96, 3);

  float hd = fl[896], hr0 = fl[897], hr1 = fl[898], hr2 = fl[899], hb = fl[900];
  for (int j = 0; j < 64; ++j) {
    float a = bf2f(actw[p * 96 + (j ^ ((p & 3) << 3))]);
    hd = fmaf(a, fl[576 + j], hd);
    hr0 = fmaf(a, fl[640 + 3 * j + 0], hr0);
    hr1 = fmaf(a, fl[640 + 3 * j + 1], hr1);
    hr2 = fmaf(a, fl[640 + 3 * j + 2], hr2);
    hb = fmaf(a, fl[832 + j], hb);
  }
  if (live) {
    size_t N4 = (size_t)Npts * 4;
    out[N4 + 3 * (size_t)n + 0] = mask ? sigmoidf_(hr0) : 0.f;
    out[N4 + 3 * (size_t)n + 1] = mask ? sigmoidf_(hr1) : 0.f;
    out[N4 + 3 * (size_t)n + 2] = mask ? sigmoidf_(hr2) : 0.f;
    out[(size_t)Npts * 7 + n] = mask ? __expf(softplusf_(hd)) : 0.f;
    out[(size_t)Npts * 8 + n] = mask ? (softplusf_(hb) + 0.1f) : 0.1f;
  }
}

extern "C" void kernel_launch(void* const* d_in, const int* in_sizes, int n_in,
                              void* d_out, int out_size, void* d_ws, size_t ws_size,
                              hipStream_t stream) {
  const int Npts = in_sizes[0] / 3;
  const float* x = (const float*)d_in[0];
  const float* d = (const float*)d_in[1];
  const int* aidx = (const int*)d_in[2];
  const int* tridx = (const int*)d_in[3];
  const float* tables = (const float*)d_in[4];
  const float* emb_a = (const float*)d_in[5];
  const float* emb_t = (const float*)d_in[6];
  const float* Wd1 = (const float*)d_in[7];
  const float* bd1 = (const float*)d_in[8];
  const float* Wd2 = (const float*)d_in[9];
  const float* bd2 = (const float*)d_in[10];
  const float* Ws1 = (const float*)d_in[11];
  const float* bs1 = (const float*)d_in[12];
  const float* Ws2 = (const float*)d_in[13];
  const float* bs2 = (const float*)d_in[14];
  const float* Ws3 = (const float*)d_in[15];
  const float* bs3 = (const float*)d_in[16];
  const float* Wt1 = (const float*)d_in[17];
  const float* bt1 = (const float*)d_in[18];
  const float* Wt2 = (const float*)d_in[19];
  const float* bt2 = (const float*)d_in[20];
  const float* Wt3 = (const float*)d_in[21];
  const float* bt3 = (const float*)d_in[22];
  const float* Wtd = (const float*)d_in[23];
  const float* btd = (const float*)d_in[24];
  const float* Wtr = (const float*)d_in[25];
  const float* btr = (const float*)d_in[26];
  const float* Wtb = (const float*)d_in[27];
  const float* btb = (const float*)d_in[28];
  float* out = (float*)d_out;

  float* hvws = (float*)d_ws;
  const size_t hv_bytes = (size_t)Npts * 16 * sizeof(float);
  unsigned short* wbuf = (unsigned short*)((char*)d_ws + hv_bytes);
  unsigned short* t8 = (unsigned short*)((char*)d_ws + hv_bytes + WBUF_BYTES);
  const size_t t8_bytes = (size_t)16 * T_SIZE * 2;
  unsigned* featws = (unsigned*)((char*)d_ws + hv_bytes + WBUF_BYTES + t8_bytes);
  const size_t feat_bytes = (size_t)Npts * 64;
  const bool has_t8 = (ws_size >= hv_bytes + WBUF_BYTES + t8_bytes);
  const bool has_f = (ws_size >= hv_bytes + WBUF_BYTES + t8_bytes + feat_bytes);

  int blocksA = ((Npts + 255) / 256) * 4;
  int blocks0 = (Npts + NT0 - 1) / NT0;
  int blocks = (Npts + NT - 1) / NT;

  if (has_f) {
    int nq = (int)(16 * T_SIZE / 2);
    kprep<<<dim3(14 + (nq + 255) / 256), dim3(256), 0, stream>>>(
        tables, (unsigned*)t8, nq, Wd1, Wd2, Ws1, Ws2, Wt1, Wt2, Wt3, wbuf);
    k0a_gather<<<dim3(blocksA), dim3(256), 0, stream>>>(x, t8, featws, Npts);
    k12b_all<<<dim3(blocks), dim3(NT), 0, stream>>>(
        x, d, aidx, tridx, emb_a, emb_t, featws, wbuf,
        bd1, bd2, bs1, bs2, Ws3, bs3, bt1, bt2, bt3,
        Wtd, btd, Wtr, btr, Wtb, btb, out, Npts);
  } else {
    kwprep<<<dim3(14), dim3(256), 0, stream>>>(Wd1, Wd2, Ws1, Ws2, Wt1, Wt2, Wt3, wbuf);
    if (has_t8) {
      int nq = (int)(16 * T_SIZE / 2);
      kconv<<<dim3((nq + 255) / 256), dim3(256), 0, stream>>>(tables, (unsigned*)t8, nq);
      k0f_density<1><<<dim3(blocks0), dim3(NT0), 0, stream>>>(
          x, tables, t8, Wd1, bd1, Wd2, bd2, hvws, out, Npts);
    } else {
      k0f_density<0><<<dim3(blocks0), dim3(NT0), 0, stream>>>(
          x, tables, t8, Wd1, bd1, Wd2, bd2, hvws, out, Npts);
    }
    k12_heads<<<dim3(blocks), dim3(NT), 0, stream>>>(
        x, d, aidx, tridx, emb_a, emb_t, wbuf,
        bs1, bs2, Ws3, bs3, bt1, bt2, bt3,
        Wtd, btd, Wtr, btr, Wtb, btb, hvws, out, Npts);
  }
}